// Round 10
// baseline (1015.708 us; speedup 1.0000x reference)
//
#include <hip/hip_runtime.h>
#include <hip/hip_bf16.h>

// Problem constants
#define NP    1024   // polynomials
#define NM    64     // monomials per poly
#define MD_   16
#define D_    512
#define NH    8
#define DH_   64
#define NL    4
#define FF_   2048
#define HID_  1024
#define NK    2048
#define EPS_  1e-5f

typedef __attribute__((ext_vector_type(8))) short short8;
typedef __attribute__((ext_vector_type(4))) float f32x4;

static __device__ __forceinline__ unsigned short f2bf(float f) {
    __hip_bfloat16 h = __float2bfloat16(f);
    return *reinterpret_cast<unsigned short*>(&h);
}

// ---------------------------------------------------------------------------
// All non-QKV weights converted in ONE launch (was 7). Segments by f4 index.
// ---------------------------------------------------------------------------
__global__ __launch_bounds__(256) void cvt_all(
    const float* __restrict__ s0, const float* __restrict__ s1,
    const float* __restrict__ s2, const float* __restrict__ s3,
    const float* __restrict__ s4, const float* __restrict__ s5,
    const float* __restrict__ s6,
    unsigned short* __restrict__ d0, unsigned short* __restrict__ d1,
    unsigned short* __restrict__ d2, unsigned short* __restrict__ d3,
    unsigned short* __restrict__ d4, unsigned short* __restrict__ d5,
    unsigned short* __restrict__ d6)
{
    const int i = blockIdx.x * 256 + threadIdx.x;   // f4 index, < 3145728
    const float* src; unsigned short* dst; int l;
    if      (i <  131072) { src = s0; dst = d0; l = i; }
    else if (i <  393216) { src = s1; dst = d1; l = i -  131072; }
    else if (i <  655360) { src = s2; dst = d2; l = i -  393216; }
    else if (i <  786432) { src = s3; dst = d3; l = i -  655360; }
    else if (i < 1048576) { src = s4; dst = d4; l = i -  786432; }
    else if (i < 2097152) { src = s5; dst = d5; l = i - 1048576; }
    else                  { src = s6; dst = d6; l = i - 2097152; }
    float4 v = *(const float4*)(src + (size_t)l * 4);
    ushort4 o;
    o.x = f2bf(v.x); o.y = f2bf(v.y); o.z = f2bf(v.z); o.w = f2bf(v.w);
    *(ushort4*)(dst + (size_t)l * 4) = o;
}

__global__ __launch_bounds__(256) void cvt_bf16_kernel(
    const float* __restrict__ in, unsigned short* __restrict__ out, int n4)
{
    const int i = blockIdx.x * 256 + threadIdx.x;
    if (i < n4) {
        float4 v = *(const float4*)(in + (size_t)i * 4);
        ushort4 o;
        o.x = f2bf(v.x); o.y = f2bf(v.y); o.z = f2bf(v.z); o.w = f2bf(v.w);
        *(ushort4*)(out + (size_t)i * 4) = o;
    }
}

// ---------------------------------------------------------------------------
// Batched QKV weight conversion + bias gather. grid (256, 3=q/k/v, 4=layer).
// ---------------------------------------------------------------------------
__global__ __launch_bounds__(256) void cvt_qkv_kernel(
    const float* __restrict__ Wq, const float* __restrict__ Wk,
    const float* __restrict__ Wv, const float* __restrict__ bq,
    const float* __restrict__ bk, const float* __restrict__ bv,
    unsigned short* __restrict__ w_qkv, float* __restrict__ b_qkvc)
{
    const int part = blockIdx.y;
    const int l    = blockIdx.z;
    const float* src  = (part == 0 ? Wq : part == 1 ? Wk : Wv) + (size_t)l * D_ * D_;
    const float* bsrc = (part == 0 ? bq : part == 1 ? bk : bv) + l * D_;
    unsigned short* dst = w_qkv + (size_t)l * 1536 * D_ + (size_t)part * 512 * D_;
    const int i = blockIdx.x * 256 + threadIdx.x;
    float4 v = *(const float4*)(src + (size_t)i * 4);
    ushort4 o;
    o.x = f2bf(v.x); o.y = f2bf(v.y); o.z = f2bf(v.z); o.w = f2bf(v.w);
    *(ushort4*)(dst + (size_t)i * 4) = o;
    if (blockIdx.x == 0) {
        b_qkvc[l * 1536 + part * 512 + threadIdx.x * 2]     = bsrc[threadIdx.x * 2];
        b_qkvc[l * 1536 + part * 512 + threadIdx.x * 2 + 1] = bsrc[threadIdx.x * 2 + 1];
    }
}

// ---------------------------------------------------------------------------
// Staging via global_load_lds, pre-swizzled source (G21). Validated round 8.
// ---------------------------------------------------------------------------
template<int ISSUES>
static __device__ __forceinline__ void stage_tile(
    const unsigned short* __restrict__ src, int ld,
    unsigned short* lds, int wave, int lane)
{
    const int rl  = lane >> 3;
    const int sw8 = (((lane & 7) ^ rl) << 3);
#pragma unroll
    for (int i = 0; i < ISSUES; ++i) {
        const int rbase = i * 32 + wave * 8;
        const unsigned short* g = src + (size_t)(rbase + rl) * ld + sw8;
        unsigned short* l = lds + rbase * 64;
        __builtin_amdgcn_global_load_lds(
            (const __attribute__((address_space(1))) void*)g,
            (__attribute__((address_space(3))) void*)l, 16, 0, 0);
    }
}

// ---------------------------------------------------------------------------
// Unified MFMA bf16 NT GEMM. MODE 0: row=by, col=bx. MODE 2: 4096-block 1-D
// XCD-aligned decode — round-9 lesson: SWAP put same-panel tiles on one XCD
// but 512 dispatch-ids apart (not co-resident). MODE 2 gives same XCD
// (id%8 = panel%8) AND spacing 8 (co-resident): lo=f&7, mid=(f>>3)&7,
// hi=f>>6; panel = hi*8+lo (row), col-tile = mid. 512 panels x 8 cols.
// ---------------------------------------------------------------------------
template<int BM, int BN, int MODE, bool OUTF32, bool BIAS, bool RELU, bool POOL, bool RESID>
__global__ __launch_bounds__(256) void mfma_nt(
    const unsigned short* __restrict__ A, long long aBatch, int lda,
    const unsigned short* __restrict__ W, long long bBatch, int ldb,
    const float* __restrict__ bias,
    const float* __restrict__ resid, int ldr,
    void* __restrict__ Cout, long long cBatch, int ldc,
    int K, float alpha)
{
    constexpr int BK = 64;
    constexpr int MI = BM / 32, NJ = BN / 32;
    __shared__ unsigned short Asl[BM * BK];
    __shared__ unsigned short Bsl[BN * BK];

    const int tid  = threadIdx.x;
    const int wave = tid >> 6, lane = tid & 63;
    const int wm = wave >> 1, wn = wave & 1;
    int row0, col0;
    if (MODE == 2) {
        const int f = blockIdx.x;
        const int lo = f & 7, mid = (f >> 3) & 7, hi = f >> 6;
        row0 = (hi * 8 + lo) * BM;
        col0 = mid * BN;
    } else {
        row0 = blockIdx.y * BM;
        col0 = blockIdx.x * BN;
    }
    const long long bz = blockIdx.z;
    A += bz * aBatch + (size_t)row0 * lda;
    W += bz * bBatch + (size_t)col0 * ldb;

    f32x4 acc[MI][NJ];
#pragma unroll
    for (int i = 0; i < MI; ++i)
#pragma unroll
        for (int j = 0; j < NJ; ++j) acc[i][j] = (f32x4){0.f, 0.f, 0.f, 0.f};

    for (int k0 = 0; k0 < K; k0 += BK) {
        stage_tile<BM / 32>(A + k0, lda, Asl, wave, lane);
        stage_tile<BN / 32>(W + k0, ldb, Bsl, wave, lane);
        __syncthreads();
#pragma unroll
        for (int ks = 0; ks < 2; ++ks) {
            short8 a[MI], b[NJ];
            const int kbase = ks * 64 + (lane >> 4) * 16;
#pragma unroll
            for (int i = 0; i < MI; ++i) {
                const int ra = wm * (BM / 2) + i * 16 + (lane & 15);
                a[i] = *(const short8*)((const char*)Asl + ra * 128 + (kbase ^ ((ra & 7) << 4)));
            }
#pragma unroll
            for (int j = 0; j < NJ; ++j) {
                const int rb = wn * (BN / 2) + j * 16 + (lane & 15);
                b[j] = *(const short8*)((const char*)Bsl + rb * 128 + (kbase ^ ((rb & 7) << 4)));
            }
#pragma unroll
            for (int i = 0; i < MI; ++i)
#pragma unroll
                for (int j = 0; j < NJ; ++j)
                    acc[i][j] = __builtin_amdgcn_mfma_f32_16x16x32_bf16(
                        a[i], b[j], acc[i][j], 0, 0, 0);
        }
        __syncthreads();
    }

    if (POOL) {
        float* red = (float*)Asl;
        red[tid] = 0.f;
        __syncthreads();
#pragma unroll
        for (int j = 0; j < NJ; ++j) {
            const int c = wn * (BN / 2) + j * 16 + (lane & 15);
            const float bi = BIAS ? bias[col0 + c] : 0.f;
            float s = 0.f;
#pragma unroll
            for (int i = 0; i < MI; ++i) {
                f32x4 v = acc[i][j];
#pragma unroll
                for (int r2 = 0; r2 < 4; ++r2) {
                    float val = v[r2] * alpha + bi;
                    if (RELU) val = fmaxf(val, 0.f);
                    s += val;
                }
            }
            atomicAdd(&red[wm * BN + c], s);
        }
        __syncthreads();
        float* C = (float*)Cout + bz * cBatch;
        const int pm = tid >> 7, c = tid & 127;
        C[(size_t)(row0 / 64 + pm) * ldc + col0 + c] = red[pm * BN + c];
    } else {
        float* Cf = (float*)Cout + (OUTF32 ? bz * cBatch : 0);
        unsigned short* Cu = (unsigned short*)Cout + (OUTF32 ? 0 : bz * cBatch);
#pragma unroll
        for (int i = 0; i < MI; ++i) {
            const int rg = row0 + wm * (BM / 2) + i * 16 + (lane >> 4) * 4;
#pragma unroll
            for (int j = 0; j < NJ; ++j) {
                const int c = col0 + wn * (BN / 2) + j * 16 + (lane & 15);
                const float bi = BIAS ? bias[c] : 0.f;
                f32x4 v = acc[i][j];
#pragma unroll
                for (int r2 = 0; r2 < 4; ++r2) {
                    float val = v[r2] * alpha + bi;
                    if (RELU) val = fmaxf(val, 0.f);
                    if (RESID) val += resid[(size_t)(rg + r2) * ldr + c];
                    if (OUTF32) Cf[(size_t)(rg + r2) * ldc + c] = val;
                    else        Cu[(size_t)(rg + r2) * ldc + c] = f2bf(val);
                }
            }
        }
    }
}

// ---------------------------------------------------------------------------
// Fused GEMM + bias + residual + LayerNorm (replaces Wo/FFN2 GEMM + ln_kernel
// + ybuf round-trip). Block = 64 rows x FULL 512 cols -> LN in epilogue.
// acc[2][16]; 4 waves 2x2 (wave tile 32x256). LDS: A 8 KB + B 64 KB.
// Writes xbuf (f32, also the resid input — same thread r/w, safe) and xb.
// ---------------------------------------------------------------------------
__global__ __launch_bounds__(256) void mfma_ln(
    const unsigned short* __restrict__ A, int lda,
    const unsigned short* __restrict__ W,
    const float* __restrict__ bias,
    const float* __restrict__ lnw, const float* __restrict__ lnb,
    float* __restrict__ xbuf, unsigned short* __restrict__ xb, int K)
{
    constexpr int BK = 64;
    __shared__ unsigned short Asl[64 * BK];    // 8 KB
    __shared__ unsigned short Bsl[512 * BK];   // 64 KB

    const int tid  = threadIdx.x;
    const int wave = tid >> 6, lane = tid & 63;
    const int wm = wave >> 1, wn = wave & 1;
    const int row0 = blockIdx.x * 64;
    A += (size_t)row0 * lda;

    f32x4 acc[2][16];
#pragma unroll
    for (int i = 0; i < 2; ++i)
#pragma unroll
        for (int j = 0; j < 16; ++j) acc[i][j] = (f32x4){0.f, 0.f, 0.f, 0.f};

    for (int k0 = 0; k0 < K; k0 += BK) {
        stage_tile<2>(A + k0, lda, Asl, wave, lane);
        stage_tile<16>(W + k0, lda == K ? K : K, Bsl, wave, lane);  // ldb == K
        __syncthreads();
#pragma unroll
        for (int ks = 0; ks < 2; ++ks) {
            const int kbase = ks * 64 + (lane >> 4) * 16;
            short8 a[2];
#pragma unroll
            for (int i = 0; i < 2; ++i) {
                const int ra = wm * 32 + i * 16 + (lane & 15);
                a[i] = *(const short8*)((const char*)Asl + ra * 128 + (kbase ^ ((ra & 7) << 4)));
            }
#pragma unroll
            for (int j = 0; j < 16; ++j) {
                const int rb = wn * 256 + j * 16 + (lane & 15);
                short8 b = *(const short8*)((const char*)Bsl + rb * 128 + (kbase ^ ((rb & 7) << 4)));
#pragma unroll
                for (int i = 0; i < 2; ++i)
                    acc[i][j] = __builtin_amdgcn_mfma_f32_16x16x32_bf16(
                        a[i], b, acc[i][j], 0, 0, 0);
            }
        }
        __syncthreads();
    }

    // Epilogue: v = acc + bias + resid; LN over each full row (512 cols).
    float* redS = (float*)Asl;          // [64]
    float* redQ = (float*)Asl + 64;     // [64]
    if (tid < 64) { redS[tid] = 0.f; redQ[tid] = 0.f; }
    __syncthreads();

#pragma unroll
    for (int i = 0; i < 2; ++i) {
#pragma unroll
        for (int r2 = 0; r2 < 4; ++r2) {
            const int lr = wm * 32 + i * 16 + (lane >> 4) * 4 + r2;
            float s1 = 0.f, s2 = 0.f;
#pragma unroll
            for (int j = 0; j < 16; ++j) {
                const int c = wn * 256 + j * 16 + (lane & 15);
                float v = acc[i][j][r2] + bias[c] +
                          xbuf[(size_t)(row0 + lr) * 512 + c];
                acc[i][j][r2] = v;
                s1 += v; s2 += v * v;
            }
            atomicAdd(&redS[lr], s1);
            atomicAdd(&redQ[lr], s2);
        }
    }
    __syncthreads();

    float lw[16], lb[16];
#pragma unroll
    for (int j = 0; j < 16; ++j) {
        const int c = wn * 256 + j * 16 + (lane & 15);
        lw[j] = lnw[c]; lb[j] = lnb[c];
    }
#pragma unroll
    for (int i = 0; i < 2; ++i) {
#pragma unroll
        for (int r2 = 0; r2 < 4; ++r2) {
            const int lr = wm * 32 + i * 16 + (lane >> 4) * 4 + r2;
            const float mu  = redS[lr] * (1.f / 512.f);
            const float var = redQ[lr] * (1.f / 512.f) - mu * mu;
            const float inv = 1.0f / sqrtf(var + EPS_);
#pragma unroll
            for (int j = 0; j < 16; ++j) {
                const int c = wn * 256 + j * 16 + (lane & 15);
                const float nv = (acc[i][j][r2] - mu) * inv * lw[j] + lb[j];
                xbuf[(size_t)(row0 + lr) * 512 + c] = nv;
                xb[(size_t)(row0 + lr) * 512 + c] = f2bf(nv);
            }
        }
    }
}

// ---------------------------------------------------------------------------
// Fused flash attention (validated round 9): block = 64 q-rows x one head.
// ---------------------------------------------------------------------------
__global__ __launch_bounds__(256) void flash_attn(
    const unsigned short* __restrict__ qkv,   // [1024][1536] (q|k|v)
    const unsigned short* __restrict__ vT,    // [512][1024]
    unsigned short* __restrict__ O)           // [1024][512]
{
    __shared__ unsigned short Qs[64 * 64];
    __shared__ unsigned short Ks[64 * 64];
    __shared__ unsigned short Ps[64 * 64];
    __shared__ unsigned short Vs[64 * 64];

    const int tid = threadIdx.x, wave = tid >> 6, lane = tid & 63;
    const int q0 = blockIdx.x * 64;
    const int h  = blockIdx.y;

    stage_tile<2>(qkv + (size_t)q0 * 1536 + h * 64, 1536, Qs, wave, lane);

    f32x4 Oacc[4];
#pragma unroll
    for (int j = 0; j < 4; ++j) Oacc[j] = (f32x4){0.f, 0.f, 0.f, 0.f};
    float mrow[4] = {-1e30f, -1e30f, -1e30f, -1e30f};
    float lrow[4] = {0.f, 0.f, 0.f, 0.f};

    for (int kt = 0; kt < 16; ++kt) {
        stage_tile<2>(qkv + 512 + (size_t)(kt * 64) * 1536 + h * 64, 1536, Ks, wave, lane);
        __syncthreads();

        f32x4 s[4];
#pragma unroll
        for (int j = 0; j < 4; ++j) s[j] = (f32x4){0.f, 0.f, 0.f, 0.f};
#pragma unroll
        for (int ks = 0; ks < 2; ++ks) {
            const int kbase = ks * 64 + (lane >> 4) * 16;
            const int ra = wave * 16 + (lane & 15);
            short8 aq = *(const short8*)((const char*)Qs + ra * 128 + (kbase ^ ((ra & 7) << 4)));
#pragma unroll
            for (int j = 0; j < 4; ++j) {
                const int rb = j * 16 + (lane & 15);
                short8 bk8 = *(const short8*)((const char*)Ks + rb * 128 + (kbase ^ ((rb & 7) << 4)));
                s[j] = __builtin_amdgcn_mfma_f32_16x16x32_bf16(aq, bk8, s[j], 0, 0, 0);
            }
        }

        float f[4];
#pragma unroll
        for (int r = 0; r < 4; ++r) {
            float mx = -1e30f;
#pragma unroll
            for (int j = 0; j < 4; ++j) { s[j][r] *= 0.125f; mx = fmaxf(mx, s[j][r]); }
#pragma unroll
            for (int o = 1; o < 16; o <<= 1) mx = fmaxf(mx, __shfl_xor(mx, o));
            const float mn = fmaxf(mrow[r], mx);
            f[r] = expf(mrow[r] - mn);
            mrow[r] = mn;
            float sm = 0.f;
#pragma unroll
            for (int j = 0; j < 4; ++j) { s[j][r] = expf(s[j][r] - mn); sm += s[j][r]; }
#pragma unroll
            for (int o = 1; o < 16; o <<= 1) sm += __shfl_xor(sm, o);
            lrow[r] = lrow[r] * f[r] + sm;
        }
#pragma unroll
        for (int j = 0; j < 4; ++j)
#pragma unroll
            for (int r = 0; r < 4; ++r) Oacc[j][r] *= f[r];

#pragma unroll
        for (int j = 0; j < 4; ++j) {
            const int col = (lane & 15) + j * 16;
#pragma unroll
            for (int r = 0; r < 4; ++r) {
                const int row = wave * 16 + (lane >> 4) * 4 + r;
                *(unsigned short*)((char*)Ps + row * 128 + ((col * 2) ^ ((row & 7) << 4))) =
                    f2bf(s[j][r]);
            }
        }

        stage_tile<2>(vT + (size_t)(h * 64) * 1024 + kt * 64, 1024, Vs, wave, lane);
        __syncthreads();

#pragma unroll
        for (int ks = 0; ks < 2; ++ks) {
            const int kbase = ks * 64 + (lane >> 4) * 16;
            const int ra = wave * 16 + (lane & 15);
            short8 ap = *(const short8*)((const char*)Ps + ra * 128 + (kbase ^ ((ra & 7) << 4)));
#pragma unroll
            for (int j = 0; j < 4; ++j) {
                const int rb = j * 16 + (lane & 15);
                short8 bv8 = *(const short8*)((const char*)Vs + rb * 128 + (kbase ^ ((rb & 7) << 4)));
                Oacc[j] = __builtin_amdgcn_mfma_f32_16x16x32_bf16(ap, bv8, Oacc[j], 0, 0, 0);
            }
        }
    }

    float linv[4];
#pragma unroll
    for (int r = 0; r < 4; ++r) linv[r] = 1.0f / lrow[r];
#pragma unroll
    for (int j = 0; j < 4; ++j) {
        const int c = h * 64 + j * 16 + (lane & 15);
#pragma unroll
        for (int r = 0; r < 4; ++r) {
            const int row = q0 + wave * 16 + (lane >> 4) * 4 + r;
            O[(size_t)row * D_ + c] = f2bf(Oacc[j][r] * linv[r]);
        }
    }
}

// ---------------------------------------------------------------------------
// bf16 transpose: in [1024][512-wide view of ldin] -> out [512][1024]
// ---------------------------------------------------------------------------
__global__ __launch_bounds__(256) void transpose_bf16(
    const unsigned short* __restrict__ in, int ldin,
    unsigned short* __restrict__ outT)
{
    __shared__ unsigned short t[32][33];
    const int r0 = blockIdx.y * 32, c0 = blockIdx.x * 32;
    const int tid = threadIdx.x;
    const int r = tid >> 3, c4 = (tid & 7) * 4;
    ushort4 v = *(const ushort4*)(in + (size_t)(r0 + r) * ldin + c0 + c4);
    t[r][c4 + 0] = v.x; t[r][c4 + 1] = v.y; t[r][c4 + 2] = v.z; t[r][c4 + 3] = v.w;
    __syncthreads();
    const int cc = tid >> 3, rr4 = (tid & 7) * 4;
    ushort4 o;
    o.x = t[rr4 + 0][cc]; o.y = t[rr4 + 1][cc]; o.z = t[rr4 + 2][cc]; o.w = t[rr4 + 3][cc];
    *(ushort4*)(outT + (size_t)(c0 + cc) * 1024 + r0 + rr4) = o;
}

// ---------------------------------------------------------------------------
// Monomial embedding -> bf16 (round-8 rewrite, validated)
// ---------------------------------------------------------------------------
__global__ __launch_bounds__(256) void embed_kernel(
    const float* __restrict__ ideal, const float* __restrict__ Wm,
    const float* __restrict__ bm, unsigned short* __restrict__ h0)
{
    __shared__ float wls[512 * 17];
    __shared__ float bls[512];
    __shared__ float irow[32 * 16];
    const int tid = threadIdx.x;
    const long long r0 = (long long)blockIdx.x * 32;
#pragma unroll
    for (int i = 0; i < 8; ++i) {
        const int f4 = i * 256 + tid;
        float4 v = *(const float4*)(Wm + (size_t)f4 * 4);
        const int e = f4 * 4;
        float* d = &wls[(e >> 4) * 17 + (e & 15)];
        d[0] = v.x; d[1] = v.y; d[2] = v.z; d[3] = v.w;
    }
    if (tid < 128) {
        *(float4*)&bls[tid * 4] = *(const float4*)(bm + tid * 4);
        *(float4*)&irow[tid * 4] = *(const float4*)(ideal + r0 * 16 + tid * 4);
    }
    __syncthreads();
    const int r = tid >> 3;
    float idv[16];
#pragma unroll
    for (int k = 0; k < 16; ++k) idv[k] = irow[r * 16 + k];
#pragma unroll
    for (int j = 0; j < 16; ++j) {
        const int c0 = (tid & 7) * 4 + j * 32;
        ushort4 o;
        unsigned short* po = (unsigned short*)&o;
#pragma unroll
        for (int q = 0; q < 4; ++q) {
            const float* w = &wls[(c0 + q) * 17];
            float s = bls[c0 + q];
#pragma unroll
            for (int k = 0; k < 16; ++k) s += idv[k] * w[k];
            po[q] = f2bf(fmaxf(s, 0.f));
        }
        *(ushort4*)(h0 + (r0 + r) * 512 + c0) = o;
    }
}

// ---------------------------------------------------------------------------
// Output fill: 0xFBFF finite under bf16/fp16/fp32 views (rounds 0-3 lesson).
// ---------------------------------------------------------------------------
__global__ __launch_bounds__(256) void fill_sentinel_bf16(unsigned short* __restrict__ out)
{
    const long long i = (long long)blockIdx.x * blockDim.x + threadIdx.x;
    const unsigned int pat = 0xFBFFFBFFu;
    uint4 v = {pat, pat, pat, pat};
    *(uint4*)(out + i * 8) = v;
}

__global__ __launch_bounds__(256) void scatter_kernel_bf16(
    const int* __restrict__ rows, const int* __restrict__ cols,
    const float* __restrict__ vals, __hip_bfloat16* __restrict__ out)
{
    const int k = blockIdx.x * blockDim.x + threadIdx.x;
    if (k < NK) {
        const int r = rows[k], c = cols[k];
        float v = vals[(long long)r * 1024 + c];
        if (!(fabsf(v) < 1e30f)) v = 0.f;   // guarantee finite output
        out[(long long)r * 1024 + c] = __float2bfloat16(v);
    }
}

// ---------------------------------------------------------------------------
extern "C" void kernel_launch(void* const* d_in, const int* in_sizes, int n_in,
                              void* d_out, int out_size, void* d_ws, size_t ws_size,
                              hipStream_t stream)
{
    const float* ideal  = (const float*)d_in[0];
    const int*   rows   = (const int*)d_in[1];
    const int*   cols   = (const int*)d_in[2];
    const float* Wm     = (const float*)d_in[3];
    const float* bm     = (const float*)d_in[4];
    const float* Wphi1  = (const float*)d_in[5];
    const float* bphi1  = (const float*)d_in[6];
    const float* Wphi2  = (const float*)d_in[7];
    const float* bphi2  = (const float*)d_in[8];
    const float* Wrho1  = (const float*)d_in[9];
    const float* brho1  = (const float*)d_in[10];
    const float* Wrho2  = (const float*)d_in[11];
    const float* brho2  = (const float*)d_in[12];
    const float* Wq     = (const float*)d_in[13];
    const float* bq     = (const float*)d_in[14];
    const float* Wk     = (const float*)d_in[15];
    const float* bk     = (const float*)d_in[16];
    const float* Wv     = (const float*)d_in[17];
    const float* bv     = (const float*)d_in[18];
    const float* Wo     = (const float*)d_in[19];
    const float* bo     = (const float*)d_in[20];
    const float* ln1w   = (const float*)d_in[21];
    const float* ln1b   = (const float*)d_in[22];
    const float* W1     = (const float*)d_in[23];
    const float* b1     = (const float*)d_in[24];
    const float* W2     = (const float*)d_in[25];
    const float* b2     = (const float*)d_in[26];
    const float* ln2w   = (const float*)d_in[27];
    const float* ln2b   = (const float*)d_in[28];
    __hip_bfloat16* out = (__hip_bfloat16*)d_out;

    // ---- Workspace (MB offsets; ws_size = 256 MiB, round-6 evidence) ----
    char* base = (char*)d_ws;
    unsigned short* w_phi1 = (unsigned short*)(base + (0ll  << 20));
    unsigned short* w_phi2 = (unsigned short*)(base + (1ll  << 20));
    unsigned short* w_rho1 = (unsigned short*)(base + (3ll  << 20));
    unsigned short* w_rho2 = (unsigned short*)(base + (5ll  << 20));
    unsigned short* w_qkv  = (unsigned short*)(base + (6ll  << 20));  // 4 x 1.5MB
    unsigned short* w_o    = (unsigned short*)(base + (12ll << 20));  // 2MB
    unsigned short* w_1    = (unsigned short*)(base + (14ll << 20));  // 8MB
    unsigned short* w_2    = (unsigned short*)(base + (22ll << 20));  // 8MB
    float*          b_qkvc = (float*)         (base + (30ll << 20));  // 24KB
    unsigned short* h0b    = (unsigned short*)(base + (31ll << 20));  // 64MB
    unsigned short* h1b    = (unsigned short*)(base + (95ll << 20));  // 128MB
    float*          sbuf   = (float*)         (base + (223ll << 20)); // 4MB
    unsigned short* sb_b   = (unsigned short*)(base + (31ll << 20));
    unsigned short* tb_b   = (unsigned short*)(base + (33ll << 20));
    float*          xbuf   = (float*)         (base + (35ll << 20));
    unsigned short* xb     = (unsigned short*)(base + (37ll << 20));
    unsigned short* qkvb   = (unsigned short*)(base + (40ll << 20));  // [1024][1536]
    unsigned short* vT     = (unsigned short*)(base + (43ll << 20));
    unsigned short* ob     = (unsigned short*)(base + (44ll << 20));
    unsigned short* ffnt   = (unsigned short*)(base + (45ll << 20));
    float*          vals   = (float*)         (base + (65ll << 20));

    // ---------------- Weight conversion (2 launches total) ----------------
    cvt_all<<<12288, 256, 0, stream>>>(Wphi1, Wphi2, Wrho1, Wrho2, Wo, W1, W2,
                                       w_phi1, w_phi2, w_rho1, w_rho2, w_o, w_1, w_2);
    cvt_qkv_kernel<<<dim3(256, 3, NL), 256, 0, stream>>>(Wq, Wk, Wv, bq, bk, bv,
                                                          w_qkv, b_qkvc);

    // ---------------- DeepSets (one-shot, XCD-aligned MODE 2) --------------
    embed_kernel<<<NP * NM / 32, 256, 0, stream>>>(ideal, Wm, bm, h0b);
    // phi1: [65536,512] @ [1024,512]^T + b, relu -> h1b ; 4096 blocks, MODE 2
    mfma_nt<128, 128, 2, false, true, true, false, false><<<4096, 256, 0, stream>>>(
        h0b, 0, D_, w_phi1, 0, D_, bphi1, nullptr, 0, h1b, 0, HID_, D_, 1.0f);
    // phi2+pool: [65536,1024] @ [1024,1024]^T + b, relu, 64-row sums -> sbuf
    mfma_nt<128, 128, 2, true, true, true, true, false><<<4096, 256, 0, stream>>>(
        h1b, 0, HID_, w_phi2, 0, HID_, bphi2, nullptr, 0, sbuf, 0, HID_, HID_, 1.0f);

    // rho (64^2 tiles)
    cvt_bf16_kernel<<<1024, 256, 0, stream>>>(sbuf, sb_b, 262144);
    mfma_nt<64, 64, 0, false, true, true, false, false><<<dim3(16, 16), 256, 0, stream>>>(
        sb_b, 0, HID_, w_rho1, 0, HID_, brho1, nullptr, 0, tb_b, 0, HID_, HID_, 1.0f);
    mfma_nt<64, 64, 0, true, true, true, false, false><<<dim3(8, 16), 256, 0, stream>>>(
        tb_b, 0, HID_, w_rho2, 0, HID_, brho2, nullptr, 0, xbuf, 0, D_, HID_, 1.0f);
    cvt_bf16_kernel<<<512, 256, 0, stream>>>(xbuf, xb, 131072);

    // ---------------- Transformer (fused QKV + flash + GEMM-LN) -----------
    for (int l = 0; l < NL; ++l) {
        // QKV fused: xb @ [Wq;Wk;Wv]^T + b -> qkvb [1024][1536]
        mfma_nt<64, 64, 0, false, true, false, false, false><<<dim3(24, 16), 256, 0, stream>>>(
            xb, 0, D_, w_qkv + (long long)l * 1536 * D_, 0, D_, b_qkvc + l * 1536,
            nullptr, 0, qkvb, 0, 1536, D_, 1.0f);
        transpose_bf16<<<dim3(16, 32), 256, 0, stream>>>(qkvb + 1024, 1536, vT);
        // fused scores+softmax+PV
        flash_attn<<<dim3(16, NH), 256, 0, stream>>>(qkvb, vT, ob);
        // x = LN1(x + ob @ Wo^T + bo)  (fused GEMM+resid+LN)
        mfma_ln<<<16, 256, 0, stream>>>(ob, D_, w_o + (long long)l * D_ * D_,
                                        bo + l * D_, ln1w + l * D_, ln1b + l * D_,
                                        xbuf, xb, D_);
        // ffn1: xb @ W1^T + b1, relu -> bf16
        mfma_nt<64, 64, 0, false, true, true, false, false><<<dim3(32, 16), 256, 0, stream>>>(
            xb, 0, D_, w_1 + (long long)l * FF_ * D_, 0, D_, b1 + l * FF_,
            nullptr, 0, ffnt, 0, FF_, D_, 1.0f);
        // x = LN2(x + ffnt @ W2^T + b2)  (fused GEMM+resid+LN)
        mfma_ln<<<16, 256, 0, stream>>>(ffnt, FF_, w_2 + (long long)l * D_ * FF_,
                                        b2 + l * D_, ln2w + l * D_, ln2b + l * D_,
                                        xbuf, xb, FF_);
    }

    // values = xb @ xb^T -> f32
    mfma_nt<64, 64, 0, true, false, false, false, false><<<dim3(16, 16), 256, 0, stream>>>(
        xb, 0, D_, xb, 0, D_, nullptr, nullptr, 0, vals, 0, NP, D_, 1.0f);

    // out (bf16) = finite sentinel everywhere, then selected entries
    fill_sentinel_bf16<<<512, 256, 0, stream>>>((unsigned short*)out);
    scatter_kernel_bf16<<<(NK + 255) / 256, 256, 0, stream>>>(rows, cols, vals, out);
}

// Round 11
// 750.605 us; speedup vs baseline: 1.3532x; 1.3532x over previous
//
#include <hip/hip_runtime.h>
#include <hip/hip_bf16.h>

// Problem constants
#define NP    1024   // polynomials
#define NM    64     // monomials per poly
#define MD_   16
#define D_    512
#define NH    8
#define DH_   64
#define NL    4
#define FF_   2048
#define HID_  1024
#define NK    2048
#define EPS_  1e-5f

typedef __attribute__((ext_vector_type(8))) short short8;
typedef __attribute__((ext_vector_type(4))) float f32x4;

static __device__ __forceinline__ unsigned short f2bf(float f) {
    __hip_bfloat16 h = __float2bfloat16(f);
    return *reinterpret_cast<unsigned short*>(&h);
}

// ---------------------------------------------------------------------------
// All non-QKV weights converted in ONE launch. Segments by f4 index.
// ---------------------------------------------------------------------------
__global__ __launch_bounds__(256) void cvt_all(
    const float* __restrict__ s0, const float* __restrict__ s1,
    const float* __restrict__ s2, const float* __restrict__ s3,
    const float* __restrict__ s4, const float* __restrict__ s5,
    const float* __restrict__ s6,
    unsigned short* __restrict__ d0, unsigned short* __restrict__ d1,
    unsigned short* __restrict__ d2, unsigned short* __restrict__ d3,
    unsigned short* __restrict__ d4, unsigned short* __restrict__ d5,
    unsigned short* __restrict__ d6)
{
    const int i = blockIdx.x * 256 + threadIdx.x;   // f4 index, < 3145728
    const float* src; unsigned short* dst; int l;
    if      (i <  131072) { src = s0; dst = d0; l = i; }
    else if (i <  393216) { src = s1; dst = d1; l = i -  131072; }
    else if (i <  655360) { src = s2; dst = d2; l = i -  393216; }
    else if (i <  786432) { src = s3; dst = d3; l = i -  655360; }
    else if (i < 1048576) { src = s4; dst = d4; l = i -  786432; }
    else if (i < 2097152) { src = s5; dst = d5; l = i - 1048576; }
    else                  { src = s6; dst = d6; l = i - 2097152; }
    float4 v = *(const float4*)(src + (size_t)l * 4);
    ushort4 o;
    o.x = f2bf(v.x); o.y = f2bf(v.y); o.z = f2bf(v.z); o.w = f2bf(v.w);
    *(ushort4*)(dst + (size_t)l * 4) = o;
}

__global__ __launch_bounds__(256) void cvt_bf16_kernel(
    const float* __restrict__ in, unsigned short* __restrict__ out, int n4)
{
    const int i = blockIdx.x * 256 + threadIdx.x;
    if (i < n4) {
        float4 v = *(const float4*)(in + (size_t)i * 4);
        ushort4 o;
        o.x = f2bf(v.x); o.y = f2bf(v.y); o.z = f2bf(v.z); o.w = f2bf(v.w);
        *(ushort4*)(out + (size_t)i * 4) = o;
    }
}

// ---------------------------------------------------------------------------
// Batched QKV weight conversion + bias gather. grid (256, 3=q/k/v, 4=layer).
// ---------------------------------------------------------------------------
__global__ __launch_bounds__(256) void cvt_qkv_kernel(
    const float* __restrict__ Wq, const float* __restrict__ Wk,
    const float* __restrict__ Wv, const float* __restrict__ bq,
    const float* __restrict__ bk, const float* __restrict__ bv,
    unsigned short* __restrict__ w_qkv, float* __restrict__ b_qkvc)
{
    const int part = blockIdx.y;
    const int l    = blockIdx.z;
    const float* src  = (part == 0 ? Wq : part == 1 ? Wk : Wv) + (size_t)l * D_ * D_;
    const float* bsrc = (part == 0 ? bq : part == 1 ? bk : bv) + l * D_;
    unsigned short* dst = w_qkv + (size_t)l * 1536 * D_ + (size_t)part * 512 * D_;
    const int i = blockIdx.x * 256 + threadIdx.x;
    float4 v = *(const float4*)(src + (size_t)i * 4);
    ushort4 o;
    o.x = f2bf(v.x); o.y = f2bf(v.y); o.z = f2bf(v.z); o.w = f2bf(v.w);
    *(ushort4*)(dst + (size_t)i * 4) = o;
    if (blockIdx.x == 0) {
        b_qkvc[l * 1536 + part * 512 + threadIdx.x * 2]     = bsrc[threadIdx.x * 2];
        b_qkvc[l * 1536 + part * 512 + threadIdx.x * 2 + 1] = bsrc[threadIdx.x * 2 + 1];
    }
}

// ---------------------------------------------------------------------------
// Staging via global_load_lds, pre-swizzled source (G21). Validated round 8.
// ---------------------------------------------------------------------------
template<int ISSUES>
static __device__ __forceinline__ void stage_tile(
    const unsigned short* __restrict__ src, int ld,
    unsigned short* lds, int wave, int lane)
{
    const int rl  = lane >> 3;
    const int sw8 = (((lane & 7) ^ rl) << 3);
#pragma unroll
    for (int i = 0; i < ISSUES; ++i) {
        const int rbase = i * 32 + wave * 8;
        const unsigned short* g = src + (size_t)(rbase + rl) * ld + sw8;
        unsigned short* l = lds + rbase * 64;
        __builtin_amdgcn_global_load_lds(
            (const __attribute__((address_space(1))) void*)g,
            (__attribute__((address_space(3))) void*)l, 16, 0, 0);
    }
}

// ---------------------------------------------------------------------------
// Unified MFMA bf16 NT GEMM. MODE 0: row=by, col=bx. MODE 2: 4096-block 1-D
// XCD-aligned decode (validated round 10: phi2 FETCH 500->83 MB): lo=f&7,
// mid=(f>>3)&7, hi=f>>6; panel=hi*8+lo (row), col-tile=mid — same-panel tiles
// share an XCD (id%8) AND are 8 ids apart (co-resident in its L2).
// ---------------------------------------------------------------------------
template<int BM, int BN, int MODE, bool OUTF32, bool BIAS, bool RELU, bool POOL, bool RESID>
__global__ __launch_bounds__(256) void mfma_nt(
    const unsigned short* __restrict__ A, long long aBatch, int lda,
    const unsigned short* __restrict__ W, long long bBatch, int ldb,
    const float* __restrict__ bias,
    const float* __restrict__ resid, int ldr,
    void* __restrict__ Cout, long long cBatch, int ldc,
    int K, float alpha)
{
    constexpr int BK = 64;
    constexpr int MI = BM / 32, NJ = BN / 32;
    __shared__ unsigned short Asl[BM * BK];
    __shared__ unsigned short Bsl[BN * BK];

    const int tid  = threadIdx.x;
    const int wave = tid >> 6, lane = tid & 63;
    const int wm = wave >> 1, wn = wave & 1;
    int row0, col0;
    if (MODE == 2) {
        const int f = blockIdx.x;
        const int lo = f & 7, mid = (f >> 3) & 7, hi = f >> 6;
        row0 = (hi * 8 + lo) * BM;
        col0 = mid * BN;
    } else {
        row0 = blockIdx.y * BM;
        col0 = blockIdx.x * BN;
    }
    const long long bz = blockIdx.z;
    A += bz * aBatch + (size_t)row0 * lda;
    W += bz * bBatch + (size_t)col0 * ldb;

    f32x4 acc[MI][NJ];
#pragma unroll
    for (int i = 0; i < MI; ++i)
#pragma unroll
        for (int j = 0; j < NJ; ++j) acc[i][j] = (f32x4){0.f, 0.f, 0.f, 0.f};

    for (int k0 = 0; k0 < K; k0 += BK) {
        stage_tile<BM / 32>(A + k0, lda, Asl, wave, lane);
        stage_tile<BN / 32>(W + k0, ldb, Bsl, wave, lane);
        __syncthreads();
#pragma unroll
        for (int ks = 0; ks < 2; ++ks) {
            short8 a[MI], b[NJ];
            const int kbase = ks * 64 + (lane >> 4) * 16;
#pragma unroll
            for (int i = 0; i < MI; ++i) {
                const int ra = wm * (BM / 2) + i * 16 + (lane & 15);
                a[i] = *(const short8*)((const char*)Asl + ra * 128 + (kbase ^ ((ra & 7) << 4)));
            }
#pragma unroll
            for (int j = 0; j < NJ; ++j) {
                const int rb = wn * (BN / 2) + j * 16 + (lane & 15);
                b[j] = *(const short8*)((const char*)Bsl + rb * 128 + (kbase ^ ((rb & 7) << 4)));
            }
#pragma unroll
            for (int i = 0; i < MI; ++i)
#pragma unroll
                for (int j = 0; j < NJ; ++j)
                    acc[i][j] = __builtin_amdgcn_mfma_f32_16x16x32_bf16(
                        a[i], b[j], acc[i][j], 0, 0, 0);
        }
        __syncthreads();
    }

    if (POOL) {
        float* red = (float*)Asl;
        red[tid] = 0.f;
        __syncthreads();
#pragma unroll
        for (int j = 0; j < NJ; ++j) {
            const int c = wn * (BN / 2) + j * 16 + (lane & 15);
            const float bi = BIAS ? bias[col0 + c] : 0.f;
            float s = 0.f;
#pragma unroll
            for (int i = 0; i < MI; ++i) {
                f32x4 v = acc[i][j];
#pragma unroll
                for (int r2 = 0; r2 < 4; ++r2) {
                    float val = v[r2] * alpha + bi;
                    if (RELU) val = fmaxf(val, 0.f);
                    s += val;
                }
            }
            atomicAdd(&red[wm * BN + c], s);
        }
        __syncthreads();
        float* C = (float*)Cout + bz * cBatch;
        const int pm = tid >> 7, c = tid & 127;
        C[(size_t)(row0 / 64 + pm) * ldc + col0 + c] = red[pm * BN + c];
    } else {
        float* Cf = (float*)Cout + (OUTF32 ? bz * cBatch : 0);
        unsigned short* Cu = (unsigned short*)Cout + (OUTF32 ? 0 : bz * cBatch);
#pragma unroll
        for (int i = 0; i < MI; ++i) {
            const int rg = row0 + wm * (BM / 2) + i * 16 + (lane >> 4) * 4;
#pragma unroll
            for (int j = 0; j < NJ; ++j) {
                const int c = col0 + wn * (BN / 2) + j * 16 + (lane & 15);
                const float bi = BIAS ? bias[c] : 0.f;
                f32x4 v = acc[i][j];
#pragma unroll
                for (int r2 = 0; r2 < 4; ++r2) {
                    float val = v[r2] * alpha + bi;
                    if (RELU) val = fmaxf(val, 0.f);
                    if (RESID) val += resid[(size_t)(rg + r2) * ldr + c];
                    if (OUTF32) Cf[(size_t)(rg + r2) * ldc + c] = val;
                    else        Cu[(size_t)(rg + r2) * ldc + c] = f2bf(val);
                }
            }
        }
    }
}

// ---------------------------------------------------------------------------
// Fused flash attention (validated round 9): block = 64 q-rows x one head.
// ---------------------------------------------------------------------------
__global__ __launch_bounds__(256) void flash_attn(
    const unsigned short* __restrict__ qkv,   // [1024][1536] (q|k|v)
    const unsigned short* __restrict__ vT,    // [512][1024]
    unsigned short* __restrict__ O)           // [1024][512]
{
    __shared__ unsigned short Qs[64 * 64];
    __shared__ unsigned short Ks[64 * 64];
    __shared__ unsigned short Ps[64 * 64];
    __shared__ unsigned short Vs[64 * 64];

    const int tid = threadIdx.x, wave = tid >> 6, lane = tid & 63;
    const int q0 = blockIdx.x * 64;
    const int h  = blockIdx.y;

    stage_tile<2>(qkv + (size_t)q0 * 1536 + h * 64, 1536, Qs, wave, lane);

    f32x4 Oacc[4];
#pragma unroll
    for (int j = 0; j < 4; ++j) Oacc[j] = (f32x4){0.f, 0.f, 0.f, 0.f};
    float mrow[4] = {-1e30f, -1e30f, -1e30f, -1e30f};
    float lrow[4] = {0.f, 0.f, 0.f, 0.f};

    for (int kt = 0; kt < 16; ++kt) {
        stage_tile<2>(qkv + 512 + (size_t)(kt * 64) * 1536 + h * 64, 1536, Ks, wave, lane);
        __syncthreads();

        f32x4 s[4];
#pragma unroll
        for (int j = 0; j < 4; ++j) s[j] = (f32x4){0.f, 0.f, 0.f, 0.f};
#pragma unroll
        for (int ks = 0; ks < 2; ++ks) {
            const int kbase = ks * 64 + (lane >> 4) * 16;
            const int ra = wave * 16 + (lane & 15);
            short8 aq = *(const short8*)((const char*)Qs + ra * 128 + (kbase ^ ((ra & 7) << 4)));
#pragma unroll
            for (int j = 0; j < 4; ++j) {
                const int rb = j * 16 + (lane & 15);
                short8 bk8 = *(const short8*)((const char*)Ks + rb * 128 + (kbase ^ ((rb & 7) << 4)));
                s[j] = __builtin_amdgcn_mfma_f32_16x16x32_bf16(aq, bk8, s[j], 0, 0, 0);
            }
        }

        float f[4];
#pragma unroll
        for (int r = 0; r < 4; ++r) {
            float mx = -1e30f;
#pragma unroll
            for (int j = 0; j < 4; ++j) { s[j][r] *= 0.125f; mx = fmaxf(mx, s[j][r]); }
#pragma unroll
            for (int o = 1; o < 16; o <<= 1) mx = fmaxf(mx, __shfl_xor(mx, o));
            const float mn = fmaxf(mrow[r], mx);
            f[r] = expf(mrow[r] - mn);
            mrow[r] = mn;
            float sm = 0.f;
#pragma unroll
            for (int j = 0; j < 4; ++j) { s[j][r] = expf(s[j][r] - mn); sm += s[j][r]; }
#pragma unroll
            for (int o = 1; o < 16; o <<= 1) sm += __shfl_xor(sm, o);
            lrow[r] = lrow[r] * f[r] + sm;
        }
#pragma unroll
        for (int j = 0; j < 4; ++j)
#pragma unroll
            for (int r = 0; r < 4; ++r) Oacc[j][r] *= f[r];

#pragma unroll
        for (int j = 0; j < 4; ++j) {
            const int col = (lane & 15) + j * 16;
#pragma unroll
            for (int r = 0; r < 4; ++r) {
                const int row = wave * 16 + (lane >> 4) * 4 + r;
                *(unsigned short*)((char*)Ps + row * 128 + ((col * 2) ^ ((row & 7) << 4))) =
                    f2bf(s[j][r]);
            }
        }

        stage_tile<2>(vT + (size_t)(h * 64) * 1024 + kt * 64, 1024, Vs, wave, lane);
        __syncthreads();

#pragma unroll
        for (int ks = 0; ks < 2; ++ks) {
            const int kbase = ks * 64 + (lane >> 4) * 16;
            const int ra = wave * 16 + (lane & 15);
            short8 ap = *(const short8*)((const char*)Ps + ra * 128 + (kbase ^ ((ra & 7) << 4)));
#pragma unroll
            for (int j = 0; j < 4; ++j) {
                const int rb = j * 16 + (lane & 15);
                short8 bv8 = *(const short8*)((const char*)Vs + rb * 128 + (kbase ^ ((rb & 7) << 4)));
                Oacc[j] = __builtin_amdgcn_mfma_f32_16x16x32_bf16(ap, bv8, Oacc[j], 0, 0, 0);
            }
        }
    }

    float linv[4];
#pragma unroll
    for (int r = 0; r < 4; ++r) linv[r] = 1.0f / lrow[r];
#pragma unroll
    for (int j = 0; j < 4; ++j) {
        const int c = h * 64 + j * 16 + (lane & 15);
#pragma unroll
        for (int r = 0; r < 4; ++r) {
            const int row = q0 + wave * 16 + (lane >> 4) * 4 + r;
            O[(size_t)row * D_ + c] = f2bf(Oacc[j][r] * linv[r]);
        }
    }
}

// ---------------------------------------------------------------------------
// bf16 transpose: in [1024][512-wide view of ldin] -> out [512][1024]
// ---------------------------------------------------------------------------
__global__ __launch_bounds__(256) void transpose_bf16(
    const unsigned short* __restrict__ in, int ldin,
    unsigned short* __restrict__ outT)
{
    __shared__ unsigned short t[32][33];
    const int r0 = blockIdx.y * 32, c0 = blockIdx.x * 32;
    const int tid = threadIdx.x;
    const int r = tid >> 3, c4 = (tid & 7) * 4;
    ushort4 v = *(const ushort4*)(in + (size_t)(r0 + r) * ldin + c0 + c4);
    t[r][c4 + 0] = v.x; t[r][c4 + 1] = v.y; t[r][c4 + 2] = v.z; t[r][c4 + 3] = v.w;
    __syncthreads();
    const int cc = tid >> 3, rr4 = (tid & 7) * 4;
    ushort4 o;
    o.x = t[rr4 + 0][cc]; o.y = t[rr4 + 1][cc]; o.z = t[rr4 + 2][cc]; o.w = t[rr4 + 3][cc];
    *(ushort4*)(outT + (size_t)(c0 + cc) * 1024 + r0 + rr4) = o;
}

// ---------------------------------------------------------------------------
// Monomial embedding -> bf16 (round-8 rewrite, validated)
// ---------------------------------------------------------------------------
__global__ __launch_bounds__(256) void embed_kernel(
    const float* __restrict__ ideal, const float* __restrict__ Wm,
    const float* __restrict__ bm, unsigned short* __restrict__ h0)
{
    __shared__ float wls[512 * 17];
    __shared__ float bls[512];
    __shared__ float irow[32 * 16];
    const int tid = threadIdx.x;
    const long long r0 = (long long)blockIdx.x * 32;
#pragma unroll
    for (int i = 0; i < 8; ++i) {
        const int f4 = i * 256 + tid;
        float4 v = *(const float4*)(Wm + (size_t)f4 * 4);
        const int e = f4 * 4;
        float* d = &wls[(e >> 4) * 17 + (e & 15)];
        d[0] = v.x; d[1] = v.y; d[2] = v.z; d[3] = v.w;
    }
    if (tid < 128) {
        *(float4*)&bls[tid * 4] = *(const float4*)(bm + tid * 4);
        *(float4*)&irow[tid * 4] = *(const float4*)(ideal + r0 * 16 + tid * 4);
    }
    __syncthreads();
    const int r = tid >> 3;
    float idv[16];
#pragma unroll
    for (int k = 0; k < 16; ++k) idv[k] = irow[r * 16 + k];
#pragma unroll
    for (int j = 0; j < 16; ++j) {
        const int c0 = (tid & 7) * 4 + j * 32;
        ushort4 o;
        unsigned short* po = (unsigned short*)&o;
#pragma unroll
        for (int q = 0; q < 4; ++q) {
            const float* w = &wls[(c0 + q) * 17];
            float s = bls[c0 + q];
#pragma unroll
            for (int k = 0; k < 16; ++k) s += idv[k] * w[k];
            po[q] = f2bf(fmaxf(s, 0.f));
        }
        *(ushort4*)(h0 + (r0 + r) * 512 + c0) = o;
    }
}

// ---------------------------------------------------------------------------
// LayerNorm over 512 elems, dual output (fp32 x + bf16 xb). One wave per row.
// (Restored from round 9 — round 10's fused mfma_ln ran 16 blocks on 256 CUs
// and regressed 200+ us; this 1024-block kernel is ~3 us.)
// ---------------------------------------------------------------------------
__global__ __launch_bounds__(64) void ln_kernel(
    const float* __restrict__ y, const float* __restrict__ w,
    const float* __restrict__ b, float* __restrict__ x,
    unsigned short* __restrict__ xb)
{
    const int row = blockIdx.x;
    const int lane = threadIdx.x;
    const float* yr = y + (long long)row * 512;
    float4 v0 = *(const float4*)(yr + lane * 8);
    float4 v1 = *(const float4*)(yr + lane * 8 + 4);
    float vals[8] = {v0.x, v0.y, v0.z, v0.w, v1.x, v1.y, v1.z, v1.w};
    float s = 0.f;
#pragma unroll
    for (int j = 0; j < 8; ++j) s += vals[j];
#pragma unroll
    for (int o = 32; o >= 1; o >>= 1) s += __shfl_xor(s, o);
    const float mu = s * (1.f / 512.f);
    float q = 0.f;
#pragma unroll
    for (int j = 0; j < 8; ++j) { float d = vals[j] - mu; q += d * d; }
#pragma unroll
    for (int o = 32; o >= 1; o >>= 1) q += __shfl_xor(q, o);
    const float inv = 1.0f / sqrtf(q * (1.f / 512.f) + EPS_);
    float ov[8];
#pragma unroll
    for (int j = 0; j < 8; ++j)
        ov[j] = (vals[j] - mu) * inv * w[lane * 8 + j] + b[lane * 8 + j];
    float4 o0 = {ov[0], ov[1], ov[2], ov[3]};
    float4 o1 = {ov[4], ov[5], ov[6], ov[7]};
    *(float4*)(x + (long long)row * 512 + lane * 8) = o0;
    *(float4*)(x + (long long)row * 512 + lane * 8 + 4) = o1;
    ushort4 u0, u1;
    u0.x = f2bf(ov[0]); u0.y = f2bf(ov[1]); u0.z = f2bf(ov[2]); u0.w = f2bf(ov[3]);
    u1.x = f2bf(ov[4]); u1.y = f2bf(ov[5]); u1.z = f2bf(ov[6]); u1.w = f2bf(ov[7]);
    *(ushort4*)(xb + (long long)row * 512 + lane * 8) = u0;
    *(ushort4*)(xb + (long long)row * 512 + lane * 8 + 4) = u1;
}

// ---------------------------------------------------------------------------
// Output fill: 0xFBFF finite under bf16/fp16/fp32 views (rounds 0-3 lesson).
// ---------------------------------------------------------------------------
__global__ __launch_bounds__(256) void fill_sentinel_bf16(unsigned short* __restrict__ out)
{
    const long long i = (long long)blockIdx.x * blockDim.x + threadIdx.x;
    const unsigned int pat = 0xFBFFFBFFu;
    uint4 v = {pat, pat, pat, pat};
    *(uint4*)(out + i * 8) = v;
}

__global__ __launch_bounds__(256) void scatter_kernel_bf16(
    const int* __restrict__ rows, const int* __restrict__ cols,
    const float* __restrict__ vals, __hip_bfloat16* __restrict__ out)
{
    const int k = blockIdx.x * blockDim.x + threadIdx.x;
    if (k < NK) {
        const int r = rows[k], c = cols[k];
        float v = vals[(long long)r * 1024 + c];
        if (!(fabsf(v) < 1e30f)) v = 0.f;   // guarantee finite output
        out[(long long)r * 1024 + c] = __float2bfloat16(v);
    }
}

// ---------------------------------------------------------------------------
extern "C" void kernel_launch(void* const* d_in, const int* in_sizes, int n_in,
                              void* d_out, int out_size, void* d_ws, size_t ws_size,
                              hipStream_t stream)
{
    const float* ideal  = (const float*)d_in[0];
    const int*   rows   = (const int*)d_in[1];
    const int*   cols   = (const int*)d_in[2];
    const float* Wm     = (const float*)d_in[3];
    const float* bm     = (const float*)d_in[4];
    const float* Wphi1  = (const float*)d_in[5];
    const float* bphi1  = (const float*)d_in[6];
    const float* Wphi2  = (const float*)d_in[7];
    const float* bphi2  = (const float*)d_in[8];
    const float* Wrho1  = (const float*)d_in[9];
    const float* brho1  = (const float*)d_in[10];
    const float* Wrho2  = (const float*)d_in[11];
    const float* brho2  = (const float*)d_in[12];
    const float* Wq     = (const float*)d_in[13];
    const float* bq     = (const float*)d_in[14];
    const float* Wk     = (const float*)d_in[15];
    const float* bk     = (const float*)d_in[16];
    const float* Wv     = (const float*)d_in[17];
    const float* bv     = (const float*)d_in[18];
    const float* Wo     = (const float*)d_in[19];
    const float* bo     = (const float*)d_in[20];
    const float* ln1w   = (const float*)d_in[21];
    const float* ln1b   = (const float*)d_in[22];
    const float* W1     = (const float*)d_in[23];
    const float* b1     = (const float*)d_in[24];
    const float* W2     = (const float*)d_in[25];
    const float* b2     = (const float*)d_in[26];
    const float* ln2w   = (const float*)d_in[27];
    const float* ln2b   = (const float*)d_in[28];
    __hip_bfloat16* out = (__hip_bfloat16*)d_out;

    // ---- Workspace (MB offsets; ws_size = 256 MiB, round-6 evidence) ----
    char* base = (char*)d_ws;
    unsigned short* w_phi1 = (unsigned short*)(base + (0ll  << 20));
    unsigned short* w_phi2 = (unsigned short*)(base + (1ll  << 20));
    unsigned short* w_rho1 = (unsigned short*)(base + (3ll  << 20));
    unsigned short* w_rho2 = (unsigned short*)(base + (5ll  << 20));
    unsigned short* w_qkv  = (unsigned short*)(base + (6ll  << 20));  // 4 x 1.5MB
    unsigned short* w_o    = (unsigned short*)(base + (12ll << 20));  // 2MB
    unsigned short* w_1    = (unsigned short*)(base + (14ll << 20));  // 8MB
    unsigned short* w_2    = (unsigned short*)(base + (22ll << 20));  // 8MB
    float*          b_qkvc = (float*)         (base + (30ll << 20));  // 24KB
    unsigned short* h0b    = (unsigned short*)(base + (31ll << 20));  // 64MB
    unsigned short* h1b    = (unsigned short*)(base + (95ll << 20));  // 128MB
    float*          sbuf   = (float*)         (base + (223ll << 20)); // 4MB
    unsigned short* sb_b   = (unsigned short*)(base + (31ll << 20));
    unsigned short* tb_b   = (unsigned short*)(base + (33ll << 20));
    float*          xbuf   = (float*)         (base + (35ll << 20));
    unsigned short* xb     = (unsigned short*)(base + (37ll << 20));
    float*          ybuf   = (float*)         (base + (38ll << 20));
    unsigned short* qkvb   = (unsigned short*)(base + (40ll << 20));  // [1024][1536]
    unsigned short* vT     = (unsigned short*)(base + (43ll << 20));
    unsigned short* ob     = (unsigned short*)(base + (44ll << 20));
    unsigned short* ffnt   = (unsigned short*)(base + (45ll << 20));
    float*          vals   = (float*)         (base + (65ll << 20));

    // ---------------- Weight conversion (2 launches total) ----------------
    cvt_all<<<12288, 256, 0, stream>>>(Wphi1, Wphi2, Wrho1, Wrho2, Wo, W1, W2,
                                       w_phi1, w_phi2, w_rho1, w_rho2, w_o, w_1, w_2);
    cvt_qkv_kernel<<<dim3(256, 3, NL), 256, 0, stream>>>(Wq, Wk, Wv, bq, bk, bv,
                                                          w_qkv, b_qkvc);

    // ---------------- DeepSets (one-shot, XCD-aligned MODE 2) --------------
    embed_kernel<<<NP * NM / 32, 256, 0, stream>>>(ideal, Wm, bm, h0b);
    // phi1: [65536,512] @ [1024,512]^T + b, relu -> h1b ; 4096 blocks, MODE 2
    mfma_nt<128, 128, 2, false, true, true, false, false><<<4096, 256, 0, stream>>>(
        h0b, 0, D_, w_phi1, 0, D_, bphi1, nullptr, 0, h1b, 0, HID_, D_, 1.0f);
    // phi2+pool: [65536,1024] @ [1024,1024]^T + b, relu, 64-row sums -> sbuf
    mfma_nt<128, 128, 2, true, true, true, true, false><<<4096, 256, 0, stream>>>(
        h1b, 0, HID_, w_phi2, 0, HID_, bphi2, nullptr, 0, sbuf, 0, HID_, HID_, 1.0f);

    // rho (64^2 tiles)
    cvt_bf16_kernel<<<1024, 256, 0, stream>>>(sbuf, sb_b, 262144);
    mfma_nt<64, 64, 0, false, true, true, false, false><<<dim3(16, 16), 256, 0, stream>>>(
        sb_b, 0, HID_, w_rho1, 0, HID_, brho1, nullptr, 0, tb_b, 0, HID_, HID_, 1.0f);
    mfma_nt<64, 64, 0, true, true, true, false, false><<<dim3(8, 16), 256, 0, stream>>>(
        tb_b, 0, HID_, w_rho2, 0, HID_, brho2, nullptr, 0, xbuf, 0, D_, HID_, 1.0f);
    cvt_bf16_kernel<<<512, 256, 0, stream>>>(xbuf, xb, 131072);

    // ---------------- Transformer (fused QKV + flash attention) -----------
    for (int l = 0; l < NL; ++l) {
        // QKV fused: xb @ [Wq;Wk;Wv]^T + b -> qkvb [1024][1536]
        mfma_nt<64, 64, 0, false, true, false, false, false><<<dim3(24, 16), 256, 0, stream>>>(
            xb, 0, D_, w_qkv + (long long)l * 1536 * D_, 0, D_, b_qkvc + l * 1536,
            nullptr, 0, qkvb, 0, 1536, D_, 1.0f);
        transpose_bf16<<<dim3(16, 32), 256, 0, stream>>>(qkvb + 1024, 1536, vT);
        // fused scores+softmax+PV
        flash_attn<<<dim3(16, NH), 256, 0, stream>>>(qkvb, vT, ob);
        // y = ob @ Wo^T + bo + x  (f32)
        mfma_nt<64, 64, 0, true, true, false, false, true><<<dim3(8, 16), 256, 0, stream>>>(
            ob, 0, D_, w_o + (long long)l * D_ * D_, 0, D_, bo + l * D_,
            xbuf, D_, ybuf, 0, D_, D_, 1.0f);
        ln_kernel<<<NP, 64, 0, stream>>>(ybuf, ln1w + l * D_, ln1b + l * D_, xbuf, xb);
        // ffn1: xb @ W1^T + b1, relu -> bf16
        mfma_nt<64, 64, 0, false, true, true, false, false><<<dim3(32, 16), 256, 0, stream>>>(
            xb, 0, D_, w_1 + (long long)l * FF_ * D_, 0, D_, b1 + l * FF_,
            nullptr, 0, ffnt, 0, FF_, D_, 1.0f);
        // ffn2: ffnt @ W2^T + b2 + x -> f32
        mfma_nt<64, 64, 0, true, true, false, false, true><<<dim3(8, 16), 256, 0, stream>>>(
            ffnt, 0, FF_, w_2 + (long long)l * D_ * FF_, 0, FF_, b2 + l * D_,
            xbuf, D_, ybuf, 0, D_, FF_, 1.0f);
        ln_kernel<<<NP, 64, 0, stream>>>(ybuf, ln2w + l * D_, ln2b + l * D_, xbuf, xb);
    }

    // values = xb @ xb^T -> f32
    mfma_nt<64, 64, 0, true, false, false, false, false><<<dim3(16, 16), 256, 0, stream>>>(
        xb, 0, D_, xb, 0, D_, nullptr, nullptr, 0, vals, 0, NP, D_, 1.0f);

    // out (bf16) = finite sentinel everywhere, then selected entries
    fill_sentinel_bf16<<<512, 256, 0, stream>>>((unsigned short*)out);
    scatter_kernel_bf16<<<(NK + 255) / 256, 256, 0, stream>>>(rows, cols, vals, out);
}

// Round 12
// 730.513 us; speedup vs baseline: 1.3904x; 1.0275x over previous
//
#include <hip/hip_runtime.h>
#include <hip/hip_bf16.h>

// Problem constants
#define NP    1024   // polynomials
#define NM    64     // monomials per poly
#define MD_   16
#define D_    512
#define NH    8
#define DH_   64
#define NL    4
#define FF_   2048
#define HID_  1024
#define NK    2048
#define EPS_  1e-5f

typedef __attribute__((ext_vector_type(8))) short short8;
typedef __attribute__((ext_vector_type(4))) float f32x4;

static __device__ __forceinline__ unsigned short f2bf(float f) {
    __hip_bfloat16 h = __float2bfloat16(f);
    return *reinterpret_cast<unsigned short*>(&h);
}
static __device__ __forceinline__ float bf2f(unsigned short u) {
    unsigned int x = ((unsigned int)u) << 16;
    return __uint_as_float(x);
}

// ---------------------------------------------------------------------------
// All non-QKV weights converted in ONE launch. Segments by f4 index.
// ---------------------------------------------------------------------------
__global__ __launch_bounds__(256) void cvt_all(
    const float* __restrict__ s0, const float* __restrict__ s1,
    const float* __restrict__ s2, const float* __restrict__ s3,
    const float* __restrict__ s4, const float* __restrict__ s5,
    const float* __restrict__ s6,
    unsigned short* __restrict__ d0, unsigned short* __restrict__ d1,
    unsigned short* __restrict__ d2, unsigned short* __restrict__ d3,
    unsigned short* __restrict__ d4, unsigned short* __restrict__ d5,
    unsigned short* __restrict__ d6)
{
    const int i = blockIdx.x * 256 + threadIdx.x;   // f4 index, < 3145728
    const float* src; unsigned short* dst; int l;
    if      (i <  131072) { src = s0; dst = d0; l = i; }
    else if (i <  393216) { src = s1; dst = d1; l = i -  131072; }
    else if (i <  655360) { src = s2; dst = d2; l = i -  393216; }
    else if (i <  786432) { src = s3; dst = d3; l = i -  655360; }
    else if (i < 1048576) { src = s4; dst = d4; l = i -  786432; }
    else if (i < 2097152) { src = s5; dst = d5; l = i - 1048576; }
    else                  { src = s6; dst = d6; l = i - 2097152; }
    float4 v = *(const float4*)(src + (size_t)l * 4);
    ushort4 o;
    o.x = f2bf(v.x); o.y = f2bf(v.y); o.z = f2bf(v.z); o.w = f2bf(v.w);
    *(ushort4*)(dst + (size_t)l * 4) = o;
}

__global__ __launch_bounds__(256) void cvt_bf16_kernel(
    const float* __restrict__ in, unsigned short* __restrict__ out, int n4)
{
    const int i = blockIdx.x * 256 + threadIdx.x;
    if (i < n4) {
        float4 v = *(const float4*)(in + (size_t)i * 4);
        ushort4 o;
        o.x = f2bf(v.x); o.y = f2bf(v.y); o.z = f2bf(v.z); o.w = f2bf(v.w);
        *(ushort4*)(out + (size_t)i * 4) = o;
    }
}

// ---------------------------------------------------------------------------
// Pad-convert [nrows][16] f32 -> [nrows][64] bf16 (cols 16..63 = 0). Lets the
// K=16 monomial embed run through the VERIFIED K%64 mfma_nt (zeros add 0).
// ---------------------------------------------------------------------------
__global__ __launch_bounds__(256) void cvt_pad64(
    const float* __restrict__ in, unsigned short* __restrict__ out, int nrows)
{
    const int tid = threadIdx.x;
    const int row = blockIdx.x * 32 + (tid >> 3);
    if (row >= nrows) return;
    const int c8 = (tid & 7) * 8;
    ushort4 o0 = {0, 0, 0, 0}, o1 = {0, 0, 0, 0};
    if (c8 < 16) {
        float4 a = *(const float4*)(in + (size_t)row * 16 + c8);
        float4 b = *(const float4*)(in + (size_t)row * 16 + c8 + 4);
        o0.x = f2bf(a.x); o0.y = f2bf(a.y); o0.z = f2bf(a.z); o0.w = f2bf(a.w);
        o1.x = f2bf(b.x); o1.y = f2bf(b.y); o1.z = f2bf(b.z); o1.w = f2bf(b.w);
    }
    *(ushort4*)(out + (size_t)row * 64 + c8) = o0;
    *(ushort4*)(out + (size_t)row * 64 + c8 + 4) = o1;
}

// ---------------------------------------------------------------------------
// Batched QKV weight conversion + bias gather. grid (256, 3=q/k/v, 4=layer).
// ---------------------------------------------------------------------------
__global__ __launch_bounds__(256) void cvt_qkv_kernel(
    const float* __restrict__ Wq, const float* __restrict__ Wk,
    const float* __restrict__ Wv, const float* __restrict__ bq,
    const float* __restrict__ bk, const float* __restrict__ bv,
    unsigned short* __restrict__ w_qkv, float* __restrict__ b_qkvc)
{
    const int part = blockIdx.y;
    const int l    = blockIdx.z;
    const float* src  = (part == 0 ? Wq : part == 1 ? Wk : Wv) + (size_t)l * D_ * D_;
    const float* bsrc = (part == 0 ? bq : part == 1 ? bk : bv) + l * D_;
    unsigned short* dst = w_qkv + (size_t)l * 1536 * D_ + (size_t)part * 512 * D_;
    const int i = blockIdx.x * 256 + threadIdx.x;
    float4 v = *(const float4*)(src + (size_t)i * 4);
    ushort4 o;
    o.x = f2bf(v.x); o.y = f2bf(v.y); o.z = f2bf(v.z); o.w = f2bf(v.w);
    *(ushort4*)(dst + (size_t)i * 4) = o;
    if (blockIdx.x == 0) {
        b_qkvc[l * 1536 + part * 512 + threadIdx.x * 2]     = bsrc[threadIdx.x * 2];
        b_qkvc[l * 1536 + part * 512 + threadIdx.x * 2 + 1] = bsrc[threadIdx.x * 2 + 1];
    }
}

// ---------------------------------------------------------------------------
// Staging via global_load_lds, pre-swizzled source (G21). Validated round 8.
// ---------------------------------------------------------------------------
template<int ISSUES>
static __device__ __forceinline__ void stage_tile(
    const unsigned short* __restrict__ src, int ld,
    unsigned short* lds, int wave, int lane)
{
    const int rl  = lane >> 3;
    const int sw8 = (((lane & 7) ^ rl) << 3);
#pragma unroll
    for (int i = 0; i < ISSUES; ++i) {
        const int rbase = i * 32 + wave * 8;
        const unsigned short* g = src + (size_t)(rbase + rl) * ld + sw8;
        unsigned short* l = lds + rbase * 64;
        __builtin_amdgcn_global_load_lds(
            (const __attribute__((address_space(1))) void*)g,
            (__attribute__((address_space(3))) void*)l, 16, 0, 0);
    }
}

// ---------------------------------------------------------------------------
// Unified MFMA bf16 NT GEMM. MODE 0: row=by, col=bx. MODE 2: 4096-block 1-D
// XCD-aligned decode (validated round 10: phi2 FETCH 500->83 MB).
// TRANSV (QKV): blocks with col0>=1024 write their C tile TRANSPOSED to
// vTout[(col0-1024)..+BN][row0..+BM] via an LDS bounce (replaces the separate
// transpose_bf16 kernel; round-12 launch-count reduction).
// ---------------------------------------------------------------------------
template<int BM, int BN, int MODE, bool OUTF32, bool BIAS, bool RELU, bool POOL,
         bool RESID, bool TRANSV>
__global__ __launch_bounds__(256) void mfma_nt(
    const unsigned short* __restrict__ A, long long aBatch, int lda,
    const unsigned short* __restrict__ W, long long bBatch, int ldb,
    const float* __restrict__ bias,
    const float* __restrict__ resid, int ldr,
    void* __restrict__ Cout, long long cBatch, int ldc,
    int K, float alpha, unsigned short* __restrict__ vTout)
{
    constexpr int BK = 64;
    constexpr int MI = BM / 32, NJ = BN / 32;
    __shared__ unsigned short Asl[BM * BK];
    __shared__ unsigned short Bsl[BN * BK];

    const int tid  = threadIdx.x;
    const int wave = tid >> 6, lane = tid & 63;
    const int wm = wave >> 1, wn = wave & 1;
    int row0, col0;
    if (MODE == 2) {
        const int f = blockIdx.x;
        const int lo = f & 7, mid = (f >> 3) & 7, hi = f >> 6;
        row0 = (hi * 8 + lo) * BM;
        col0 = mid * BN;
    } else {
        row0 = blockIdx.y * BM;
        col0 = blockIdx.x * BN;
    }
    const long long bz = blockIdx.z;
    A += bz * aBatch + (size_t)row0 * lda;
    W += bz * bBatch + (size_t)col0 * ldb;

    f32x4 acc[MI][NJ];
#pragma unroll
    for (int i = 0; i < MI; ++i)
#pragma unroll
        for (int j = 0; j < NJ; ++j) acc[i][j] = (f32x4){0.f, 0.f, 0.f, 0.f};

    for (int k0 = 0; k0 < K; k0 += BK) {
        stage_tile<BM / 32>(A + k0, lda, Asl, wave, lane);
        stage_tile<BN / 32>(W + k0, ldb, Bsl, wave, lane);
        __syncthreads();
#pragma unroll
        for (int ks = 0; ks < 2; ++ks) {
            short8 a[MI], b[NJ];
            const int kbase = ks * 64 + (lane >> 4) * 16;
#pragma unroll
            for (int i = 0; i < MI; ++i) {
                const int ra = wm * (BM / 2) + i * 16 + (lane & 15);
                a[i] = *(const short8*)((const char*)Asl + ra * 128 + (kbase ^ ((ra & 7) << 4)));
            }
#pragma unroll
            for (int j = 0; j < NJ; ++j) {
                const int rb = wn * (BN / 2) + j * 16 + (lane & 15);
                b[j] = *(const short8*)((const char*)Bsl + rb * 128 + (kbase ^ ((rb & 7) << 4)));
            }
#pragma unroll
            for (int i = 0; i < MI; ++i)
#pragma unroll
                for (int j = 0; j < NJ; ++j)
                    acc[i][j] = __builtin_amdgcn_mfma_f32_16x16x32_bf16(
                        a[i], b[j], acc[i][j], 0, 0, 0);
        }
        __syncthreads();
    }

    if (POOL) {
        float* red = (float*)Asl;
        red[tid] = 0.f;
        __syncthreads();
#pragma unroll
        for (int j = 0; j < NJ; ++j) {
            const int c = wn * (BN / 2) + j * 16 + (lane & 15);
            const float bi = BIAS ? bias[col0 + c] : 0.f;
            float s = 0.f;
#pragma unroll
            for (int i = 0; i < MI; ++i) {
                f32x4 v = acc[i][j];
#pragma unroll
                for (int r2 = 0; r2 < 4; ++r2) {
                    float val = v[r2] * alpha + bi;
                    if (RELU) val = fmaxf(val, 0.f);
                    s += val;
                }
            }
            atomicAdd(&red[wm * BN + c], s);
        }
        __syncthreads();
        float* C = (float*)Cout + bz * cBatch;
        const int pm = tid >> 7, c = tid & 127;
        C[(size_t)(row0 / 64 + pm) * ldc + col0 + c] = red[pm * BN + c];
    } else if (TRANSV && col0 >= 1024) {
        // V region of the fused QKV: write C transposed to vT via LDS bounce.
        unsigned short* tr = Asl;   // [BM][BN] = 64x64 ushort = 8 KB (dead LDS)
#pragma unroll
        for (int i = 0; i < MI; ++i) {
            const int rr = wm * (BM / 2) + i * 16 + (lane >> 4) * 4;
#pragma unroll
            for (int j = 0; j < NJ; ++j) {
                const int c = wn * (BN / 2) + j * 16 + (lane & 15);
                const float bi = BIAS ? bias[col0 + c] : 0.f;
                f32x4 v = acc[i][j];
#pragma unroll
                for (int r2 = 0; r2 < 4; ++r2)
                    tr[(rr + r2) * BN + c] = f2bf(v[r2] * alpha + bi);
            }
        }
        __syncthreads();
        const int c  = tid >> 2;          // local col = vT row
        const int r4 = (tid & 3) * 16;    // 16-row chunk
        ushort4 o[4];
#pragma unroll
        for (int e = 0; e < 16; ++e)
            ((unsigned short*)o)[e] = tr[(r4 + e) * BN + c];
        unsigned short* dst = vTout + (size_t)(col0 - 1024 + c) * 1024 + row0 + r4;
        *(ushort4*)(dst + 0)  = o[0];
        *(ushort4*)(dst + 4)  = o[1];
        *(ushort4*)(dst + 8)  = o[2];
        *(ushort4*)(dst + 12) = o[3];
    } else {
        float* Cf = (float*)Cout + (OUTF32 ? bz * cBatch : 0);
        unsigned short* Cu = (unsigned short*)Cout + (OUTF32 ? 0 : bz * cBatch);
#pragma unroll
        for (int i = 0; i < MI; ++i) {
            const int rg = row0 + wm * (BM / 2) + i * 16 + (lane >> 4) * 4;
#pragma unroll
            for (int j = 0; j < NJ; ++j) {
                const int c = col0 + wn * (BN / 2) + j * 16 + (lane & 15);
                const float bi = BIAS ? bias[c] : 0.f;
                f32x4 v = acc[i][j];
#pragma unroll
                for (int r2 = 0; r2 < 4; ++r2) {
                    float val = v[r2] * alpha + bi;
                    if (RELU) val = fmaxf(val, 0.f);
                    if (RESID) val += resid[(size_t)(rg + r2) * ldr + c];
                    if (OUTF32) Cf[(size_t)(rg + r2) * ldc + c] = val;
                    else        Cu[(size_t)(rg + r2) * ldc + c] = f2bf(val);
                }
            }
        }
    }
}

// ---------------------------------------------------------------------------
// Fused flash attention (validated round 9): block = 64 q-rows x one head.
// ---------------------------------------------------------------------------
__global__ __launch_bounds__(256) void flash_attn(
    const unsigned short* __restrict__ qkv,   // [1024][1536] (q|k|v)
    const unsigned short* __restrict__ vT,    // [512][1024]
    unsigned short* __restrict__ O)           // [1024][512]
{
    __shared__ unsigned short Qs[64 * 64];
    __shared__ unsigned short Ks[64 * 64];
    __shared__ unsigned short Ps[64 * 64];
    __shared__ unsigned short Vs[64 * 64];

    const int tid = threadIdx.x, wave = tid >> 6, lane = tid & 63;
    const int q0 = blockIdx.x * 64;
    const int h  = blockIdx.y;

    stage_tile<2>(qkv + (size_t)q0 * 1536 + h * 64, 1536, Qs, wave, lane);

    f32x4 Oacc[4];
#pragma unroll
    for (int j = 0; j < 4; ++j) Oacc[j] = (f32x4){0.f, 0.f, 0.f, 0.f};
    float mrow[4] = {-1e30f, -1e30f, -1e30f, -1e30f};
    float lrow[4] = {0.f, 0.f, 0.f, 0.f};

    for (int kt = 0; kt < 16; ++kt) {
        stage_tile<2>(qkv + 512 + (size_t)(kt * 64) * 1536 + h * 64, 1536, Ks, wave, lane);
        __syncthreads();

        f32x4 s[4];
#pragma unroll
        for (int j = 0; j < 4; ++j) s[j] = (f32x4){0.f, 0.f, 0.f, 0.f};
#pragma unroll
        for (int ks = 0; ks < 2; ++ks) {
            const int kbase = ks * 64 + (lane >> 4) * 16;
            const int ra = wave * 16 + (lane & 15);
            short8 aq = *(const short8*)((const char*)Qs + ra * 128 + (kbase ^ ((ra & 7) << 4)));
#pragma unroll
            for (int j = 0; j < 4; ++j) {
                const int rb = j * 16 + (lane & 15);
                short8 bk8 = *(const short8*)((const char*)Ks + rb * 128 + (kbase ^ ((rb & 7) << 4)));
                s[j] = __builtin_amdgcn_mfma_f32_16x16x32_bf16(aq, bk8, s[j], 0, 0, 0);
            }
        }

        float f[4];
#pragma unroll
        for (int r = 0; r < 4; ++r) {
            float mx = -1e30f;
#pragma unroll
            for (int j = 0; j < 4; ++j) { s[j][r] *= 0.125f; mx = fmaxf(mx, s[j][r]); }
#pragma unroll
            for (int o = 1; o < 16; o <<= 1) mx = fmaxf(mx, __shfl_xor(mx, o));
            const float mn = fmaxf(mrow[r], mx);
            f[r] = expf(mrow[r] - mn);
            mrow[r] = mn;
            float sm = 0.f;
#pragma unroll
            for (int j = 0; j < 4; ++j) { s[j][r] = expf(s[j][r] - mn); sm += s[j][r]; }
#pragma unroll
            for (int o = 1; o < 16; o <<= 1) sm += __shfl_xor(sm, o);
            lrow[r] = lrow[r] * f[r] + sm;
        }
#pragma unroll
        for (int j = 0; j < 4; ++j)
#pragma unroll
            for (int r = 0; r < 4; ++r) Oacc[j][r] *= f[r];

#pragma unroll
        for (int j = 0; j < 4; ++j) {
            const int col = (lane & 15) + j * 16;
#pragma unroll
            for (int r = 0; r < 4; ++r) {
                const int row = wave * 16 + (lane >> 4) * 4 + r;
                *(unsigned short*)((char*)Ps + row * 128 + ((col * 2) ^ ((row & 7) << 4))) =
                    f2bf(s[j][r]);
            }
        }

        stage_tile<2>(vT + (size_t)(h * 64) * 1024 + kt * 64, 1024, Vs, wave, lane);
        __syncthreads();

#pragma unroll
        for (int ks = 0; ks < 2; ++ks) {
            const int kbase = ks * 64 + (lane >> 4) * 16;
            const int ra = wave * 16 + (lane & 15);
            short8 ap = *(const short8*)((const char*)Ps + ra * 128 + (kbase ^ ((ra & 7) << 4)));
#pragma unroll
            for (int j = 0; j < 4; ++j) {
                const int rb = j * 16 + (lane & 15);
                short8 bv8 = *(const short8*)((const char*)Vs + rb * 128 + (kbase ^ ((rb & 7) << 4)));
                Oacc[j] = __builtin_amdgcn_mfma_f32_16x16x32_bf16(ap, bv8, Oacc[j], 0, 0, 0);
            }
        }
    }

    float linv[4];
#pragma unroll
    for (int r = 0; r < 4; ++r) linv[r] = 1.0f / lrow[r];
#pragma unroll
    for (int j = 0; j < 4; ++j) {
        const int c = h * 64 + j * 16 + (lane & 15);
#pragma unroll
        for (int r = 0; r < 4; ++r) {
            const int row = q0 + wave * 16 + (lane >> 4) * 4 + r;
            O[(size_t)row * D_ + c] = f2bf(Oacc[j][r] * linv[r]);
        }
    }
}

// ---------------------------------------------------------------------------
// LayerNorm over 512 elems, dual output (fp32 x + bf16 xb). One wave per row.
// ---------------------------------------------------------------------------
__global__ __launch_bounds__(64) void ln_kernel(
    const float* __restrict__ y, const float* __restrict__ w,
    const float* __restrict__ b, float* __restrict__ x,
    unsigned short* __restrict__ xb)
{
    const int row = blockIdx.x;
    const int lane = threadIdx.x;
    const float* yr = y + (long long)row * 512;
    float4 v0 = *(const float4*)(yr + lane * 8);
    float4 v1 = *(const float4*)(yr + lane * 8 + 4);
    float vals[8] = {v0.x, v0.y, v0.z, v0.w, v1.x, v1.y, v1.z, v1.w};
    float s = 0.f;
#pragma unroll
    for (int j = 0; j < 8; ++j) s += vals[j];
#pragma unroll
    for (int o = 32; o >= 1; o >>= 1) s += __shfl_xor(s, o);
    const float mu = s * (1.f / 512.f);
    float q = 0.f;
#pragma unroll
    for (int j = 0; j < 8; ++j) { float d = vals[j] - mu; q += d * d; }
#pragma unroll
    for (int o = 32; o >= 1; o >>= 1) q += __shfl_xor(q, o);
    const float inv = 1.0f / sqrtf(q * (1.f / 512.f) + EPS_);
    float ov[8];
#pragma unroll
    for (int j = 0; j < 8; ++j)
        ov[j] = (vals[j] - mu) * inv * w[lane * 8 + j] + b[lane * 8 + j];
    float4 o0 = {ov[0], ov[1], ov[2], ov[3]};
    float4 o1 = {ov[4], ov[5], ov[6], ov[7]};
    *(float4*)(x + (long long)row * 512 + lane * 8) = o0;
    *(float4*)(x + (long long)row * 512 + lane * 8 + 4) = o1;
    ushort4 u0, u1;
    u0.x = f2bf(ov[0]); u0.y = f2bf(ov[1]); u0.z = f2bf(ov[2]); u0.w = f2bf(ov[3]);
    u1.x = f2bf(ov[4]); u1.y = f2bf(ov[5]); u1.z = f2bf(ov[6]); u1.w = f2bf(ov[7]);
    *(ushort4*)(xb + (long long)row * 512 + lane * 8) = u0;
    *(ushort4*)(xb + (long long)row * 512 + lane * 8 + 4) = u1;
}

// ---------------------------------------------------------------------------
// Output fill: 0xFBFF finite under bf16/fp16/fp32 views (rounds 0-3 lesson).
// ---------------------------------------------------------------------------
__global__ __launch_bounds__(256) void fill_sentinel_bf16(unsigned short* __restrict__ out)
{
    const long long i = (long long)blockIdx.x * blockDim.x + threadIdx.x;
    const unsigned int pat = 0xFBFFFBFFu;
    uint4 v = {pat, pat, pat, pat};
    *(uint4*)(out + i * 8) = v;
}

// ---------------------------------------------------------------------------
// Fused values+scatter: only the 2048 selected (r,c) entries of x@x^T are ever
// read — compute exactly those. One wave per pair: 512-dim bf16 dot, fp32
// accum, shfl reduce. Replaces the 1.07 GF values GEMM + vals buffer.
// ---------------------------------------------------------------------------
__global__ __launch_bounds__(256) void scatter_dot(
    const int* __restrict__ rows, const int* __restrict__ cols,
    const unsigned short* __restrict__ xb, __hip_bfloat16* __restrict__ out)
{
    const int k = blockIdx.x * 4 + (threadIdx.x >> 6);
    const int lane = threadIdx.x & 63;
    const int r = rows[k], c = cols[k];
    const unsigned short* xr = xb + (size_t)r * 512 + lane * 8;
    const unsigned short* xc = xb + (size_t)c * 512 + lane * 8;
    ushort4 a0 = *(const ushort4*)xr, a1 = *(const ushort4*)(xr + 4);
    ushort4 b0 = *(const ushort4*)xc, b1 = *(const ushort4*)(xc + 4);
    float s = bf2f(a0.x) * bf2f(b0.x) + bf2f(a0.y) * bf2f(b0.y) +
              bf2f(a0.z) * bf2f(b0.z) + bf2f(a0.w) * bf2f(b0.w) +
              bf2f(a1.x) * bf2f(b1.x) + bf2f(a1.y) * bf2f(b1.y) +
              bf2f(a1.z) * bf2f(b1.z) + bf2f(a1.w) * bf2f(b1.w);
#pragma unroll
    for (int o = 32; o >= 1; o >>= 1) s += __shfl_xor(s, o);
    if (lane == 0) {
        if (!(fabsf(s) < 1e30f)) s = 0.f;   // guarantee finite output
        out[(size_t)r * 1024 + c] = __float2bfloat16(s);
    }
}

// ---------------------------------------------------------------------------
extern "C" void kernel_launch(void* const* d_in, const int* in_sizes, int n_in,
                              void* d_out, int out_size, void* d_ws, size_t ws_size,
                              hipStream_t stream)
{
    const float* ideal  = (const float*)d_in[0];
    const int*   rows   = (const int*)d_in[1];
    const int*   cols   = (const int*)d_in[2];
    const float* Wm     = (const float*)d_in[3];
    const float* bm     = (const float*)d_in[4];
    const float* Wphi1  = (const float*)d_in[5];
    const float* bphi1  = (const float*)d_in[6];
    const float* Wphi2  = (const float*)d_in[7];
    const float* bphi2  = (const float*)d_in[8];
    const float* Wrho1  = (const float*)d_in[9];
    const float* brho1  = (const float*)d_in[10];
    const float* Wrho2  = (const float*)d_in[11];
    const float* brho2  = (const float*)d_in[12];
    const float* Wq     = (const float*)d_in[13];
    const float* bq     = (const float*)d_in[14];
    const float* Wk     = (const float*)d_in[15];
    const float* bk     = (const float*)d_in[16];
    const float* Wv     = (const float*)d_in[17];
    const float* bv     = (const float*)d_in[18];
    const float* Wo     = (const float*)d_in[19];
    const float* bo     = (const float*)d_in[20];
    const float* ln1w   = (const float*)d_in[21];
    const float* ln1b   = (const float*)d_in[22];
    const float* W1     = (const float*)d_in[23];
    const float* b1     = (const float*)d_in[24];
    const float* W2     = (const float*)d_in[25];
    const float* b2     = (const float*)d_in[26];
    const float* ln2w   = (const float*)d_in[27];
    const float* ln2b   = (const float*)d_in[28];
    __hip_bfloat16* out = (__hip_bfloat16*)d_out;

    // ---- Workspace (MB offsets; ws_size = 256 MiB, round-6 evidence) ----
    char* base = (char*)d_ws;
    unsigned short* w_phi1 = (unsigned short*)(base + (0ll  << 20));
    unsigned short* w_phi2 = (unsigned short*)(base + (1ll  << 20));
    unsigned short* w_rho1 = (unsigned short*)(base + (3ll  << 20));
    unsigned short* w_rho2 = (unsigned short*)(base + (5ll  << 20));
    unsigned short* w_qkv  = (unsigned short*)(base + (6ll  << 20));  // 4 x 1.5MB
    unsigned short* w_o    = (unsigned short*)(base + (12ll << 20));  // 2MB
    unsigned short* w_1    = (unsigned short*)(base + (14ll << 20));  // 8MB
    unsigned short* w_2    = (unsigned short*)(base + (22ll << 20));  // 8MB
    float*          b_qkvc = (float*)         (base + (30ll << 20));  // 24KB
    unsigned short* h0b    = (unsigned short*)(base + (31ll << 20));  // 64MB
    unsigned short* h1b    = (unsigned short*)(base + (95ll << 20));  // 128MB
    float*          sbuf   = (float*)         (base + (223ll << 20)); // 4MB
    unsigned short* id_pad = (unsigned short*)(base + (227ll << 20)); // 8MB
    unsigned short* wm_pad = (unsigned short*)(base + (236ll << 20)); // 64KB
    unsigned short* sb_b   = (unsigned short*)(base + (31ll << 20));
    unsigned short* tb_b   = (unsigned short*)(base + (33ll << 20));
    float*          xbuf   = (float*)         (base + (35ll << 20));
    unsigned short* xb     = (unsigned short*)(base + (37ll << 20));
    float*          ybuf   = (float*)         (base + (38ll << 20));
    unsigned short* qkvb   = (unsigned short*)(base + (40ll << 20));  // [1024][1536]
    unsigned short* vT     = (unsigned short*)(base + (43ll << 20));
    unsigned short* ob     = (unsigned short*)(base + (44ll << 20));
    unsigned short* ffnt   = (unsigned short*)(base + (45ll << 20));

    // ---------------- Output fill first (independent of everything) --------
    fill_sentinel_bf16<<<512, 256, 0, stream>>>((unsigned short*)out);

    // ---------------- Weight conversion ----------------
    cvt_all<<<12288, 256, 0, stream>>>(Wphi1, Wphi2, Wrho1, Wrho2, Wo, W1, W2,
                                       w_phi1, w_phi2, w_rho1, w_rho2, w_o, w_1, w_2);
    cvt_qkv_kernel<<<dim3(256, 3, NL), 256, 0, stream>>>(Wq, Wk, Wv, bq, bk, bv,
                                                          w_qkv, b_qkvc);
    cvt_pad64<<<2048, 256, 0, stream>>>(ideal, id_pad, NP * NM);
    cvt_pad64<<<16, 256, 0, stream>>>(Wm, wm_pad, D_);

    // ---------------- DeepSets ----------------
    // embed as K=64 MFMA GEMM (zeros beyond k=16 add nothing): replaces the
    // 50 us VALU-bound embed kernel (round-12 change).
    mfma_nt<128, 128, 0, false, true, true, false, false, false><<<dim3(4, 512), 256, 0, stream>>>(
        id_pad, 0, 64, wm_pad, 0, 64, bm, nullptr, 0, h0b, 0, D_, 64, 1.0f, nullptr);
    // phi1: [65536,512] @ [1024,512]^T + b, relu -> h1b ; 4096 blocks, MODE 2
    mfma_nt<128, 128, 2, false, true, true, false, false, false><<<4096, 256, 0, stream>>>(
        h0b, 0, D_, w_phi1, 0, D_, bphi1, nullptr, 0, h1b, 0, HID_, D_, 1.0f, nullptr);
    // phi2+pool: [65536,1024] @ [1024,1024]^T + b, relu, 64-row sums -> sbuf
    mfma_nt<128, 128, 2, true, true, true, true, false, false><<<4096, 256, 0, stream>>>(
        h1b, 0, HID_, w_phi2, 0, HID_, bphi2, nullptr, 0, sbuf, 0, HID_, HID_, 1.0f, nullptr);

    // rho (64^2 tiles)
    cvt_bf16_kernel<<<1024, 256, 0, stream>>>(sbuf, sb_b, 262144);
    mfma_nt<64, 64, 0, false, true, true, false, false, false><<<dim3(16, 16), 256, 0, stream>>>(
        sb_b, 0, HID_, w_rho1, 0, HID_, brho1, nullptr, 0, tb_b, 0, HID_, HID_, 1.0f, nullptr);
    mfma_nt<64, 64, 0, true, true, true, false, false, false><<<dim3(8, 16), 256, 0, stream>>>(
        tb_b, 0, HID_, w_rho2, 0, HID_, brho2, nullptr, 0, xbuf, 0, D_, HID_, 1.0f, nullptr);
    cvt_bf16_kernel<<<512, 256, 0, stream>>>(xbuf, xb, 131072);

    // ---------------- Transformer (fused QKV+V-transpose + flash) -----------
    for (int l = 0; l < NL; ++l) {
        // QKV fused: xb @ [Wq;Wk;Wv]^T + b -> qkvb [1024][1536]; V-region
        // blocks (col0>=1024) write vT directly (TRANSV).
        mfma_nt<64, 64, 0, false, true, false, false, false, true><<<dim3(24, 16), 256, 0, stream>>>(
            xb, 0, D_, w_qkv + (long long)l * 1536 * D_, 0, D_, b_qkvc + l * 1536,
            nullptr, 0, qkvb, 0, 1536, D_, 1.0f, vT);
        // fused scores+softmax+PV
        flash_attn<<<dim3(16, NH), 256, 0, stream>>>(qkvb, vT, ob);
        // y = ob @ Wo^T + bo + x  (f32)
        mfma_nt<64, 64, 0, true, true, false, false, true, false><<<dim3(8, 16), 256, 0, stream>>>(
            ob, 0, D_, w_o + (long long)l * D_ * D_, 0, D_, bo + l * D_,
            xbuf, D_, ybuf, 0, D_, D_, 1.0f, nullptr);
        ln_kernel<<<NP, 64, 0, stream>>>(ybuf, ln1w + l * D_, ln1b + l * D_, xbuf, xb);
        // ffn1: xb @ W1^T + b1, relu -> bf16
        mfma_nt<64, 64, 0, false, true, true, false, false, false><<<dim3(32, 16), 256, 0, stream>>>(
            xb, 0, D_, w_1 + (long long)l * FF_ * D_, 0, D_, b1 + l * FF_,
            nullptr, 0, ffnt, 0, FF_, D_, 1.0f, nullptr);
        // ffn2: ffnt @ W2^T + b2 + x -> f32
        mfma_nt<64, 64, 0, true, true, false, false, true, false><<<dim3(8, 16), 256, 0, stream>>>(
            ffnt, 0, FF_, w_2 + (long long)l * D_ * FF_, 0, FF_, b2 + l * D_,
            xbuf, D_, ybuf, 0, D_, FF_, 1.0f, nullptr);
        ln_kernel<<<NP, 64, 0, stream>>>(ybuf, ln2w + l * D_, ln2b + l * D_, xbuf, xb);
    }

    // scatter: out[r,c] = dot(x[r], x[c]) for the 2048 selected pairs only
    scatter_dot<<<NK / 4, 256, 0, stream>>>(rows, cols, xb, out);
}

// Round 13
// 646.265 us; speedup vs baseline: 1.5717x; 1.1304x over previous
//
#include <hip/hip_runtime.h>
#include <hip/hip_bf16.h>

// Problem constants
#define NP    1024   // polynomials
#define NM    64     // monomials per poly
#define MD_   16
#define D_    512
#define NH    8
#define DH_   64
#define NL    4
#define FF_   2048
#define HID_  1024
#define NK    2048
#define EPS_  1e-5f

typedef __attribute__((ext_vector_type(8))) short short8;
typedef __attribute__((ext_vector_type(4))) float f32x4;

static __device__ __forceinline__ unsigned short f2bf(float f) {
    __hip_bfloat16 h = __float2bfloat16(f);
    return *reinterpret_cast<unsigned short*>(&h);
}
static __device__ __forceinline__ float bf2f(unsigned short u) {
    unsigned int x = ((unsigned int)u) << 16;
    return __uint_as_float(x);
}

// ---------------------------------------------------------------------------
// All non-QKV weights converted in ONE launch. Segments by f4 index.
// ---------------------------------------------------------------------------
__global__ __launch_bounds__(256) void cvt_all(
    const float* __restrict__ s0, const float* __restrict__ s1,
    const float* __restrict__ s2, const float* __restrict__ s3,
    const float* __restrict__ s4, const float* __restrict__ s5,
    const float* __restrict__ s6,
    unsigned short* __restrict__ d0, unsigned short* __restrict__ d1,
    unsigned short* __restrict__ d2, unsigned short* __restrict__ d3,
    unsigned short* __restrict__ d4, unsigned short* __restrict__ d5,
    unsigned short* __restrict__ d6)
{
    const int i = blockIdx.x * 256 + threadIdx.x;   // f4 index, < 3145728
    const float* src; unsigned short* dst; int l;
    if      (i <  131072) { src = s0; dst = d0; l = i; }
    else if (i <  393216) { src = s1; dst = d1; l = i -  131072; }
    else if (i <  655360) { src = s2; dst = d2; l = i -  393216; }
    else if (i <  786432) { src = s3; dst = d3; l = i -  655360; }
    else if (i < 1048576) { src = s4; dst = d4; l = i -  786432; }
    else if (i < 2097152) { src = s5; dst = d5; l = i - 1048576; }
    else                  { src = s6; dst = d6; l = i - 2097152; }
    float4 v = *(const float4*)(src + (size_t)l * 4);
    ushort4 o;
    o.x = f2bf(v.x); o.y = f2bf(v.y); o.z = f2bf(v.z); o.w = f2bf(v.w);
    *(ushort4*)(dst + (size_t)l * 4) = o;
}

__global__ __launch_bounds__(256) void cvt_bf16_kernel(
    const float* __restrict__ in, unsigned short* __restrict__ out, int n4)
{
    const int i = blockIdx.x * 256 + threadIdx.x;
    if (i < n4) {
        float4 v = *(const float4*)(in + (size_t)i * 4);
        ushort4 o;
        o.x = f2bf(v.x); o.y = f2bf(v.y); o.z = f2bf(v.z); o.w = f2bf(v.w);
        *(ushort4*)(out + (size_t)i * 4) = o;
    }
}

// ---------------------------------------------------------------------------
// Pad-convert [nrows][16] f32 -> [nrows][64] bf16 (cols 16..63 = 0).
// ---------------------------------------------------------------------------
__global__ __launch_bounds__(256) void cvt_pad64(
    const float* __restrict__ in, unsigned short* __restrict__ out, int nrows)
{
    const int tid = threadIdx.x;
    const int row = blockIdx.x * 32 + (tid >> 3);
    if (row >= nrows) return;
    const int c8 = (tid & 7) * 8;
    ushort4 o0 = {0, 0, 0, 0}, o1 = {0, 0, 0, 0};
    if (c8 < 16) {
        float4 a = *(const float4*)(in + (size_t)row * 16 + c8);
        float4 b = *(const float4*)(in + (size_t)row * 16 + c8 + 4);
        o0.x = f2bf(a.x); o0.y = f2bf(a.y); o0.z = f2bf(a.z); o0.w = f2bf(a.w);
        o1.x = f2bf(b.x); o1.y = f2bf(b.y); o1.z = f2bf(b.z); o1.w = f2bf(b.w);
    }
    *(ushort4*)(out + (size_t)row * 64 + c8) = o0;
    *(ushort4*)(out + (size_t)row * 64 + c8 + 4) = o1;
}

// ---------------------------------------------------------------------------
// Batched QKV weight conversion + bias gather. grid (256, 3=q/k/v, 4=layer).
// ---------------------------------------------------------------------------
__global__ __launch_bounds__(256) void cvt_qkv_kernel(
    const float* __restrict__ Wq, const float* __restrict__ Wk,
    const float* __restrict__ Wv, const float* __restrict__ bq,
    const float* __restrict__ bk, const float* __restrict__ bv,
    unsigned short* __restrict__ w_qkv, float* __restrict__ b_qkvc)
{
    const int part = blockIdx.y;
    const int l    = blockIdx.z;
    const float* src  = (part == 0 ? Wq : part == 1 ? Wk : Wv) + (size_t)l * D_ * D_;
    const float* bsrc = (part == 0 ? bq : part == 1 ? bk : bv) + l * D_;
    unsigned short* dst = w_qkv + (size_t)l * 1536 * D_ + (size_t)part * 512 * D_;
    const int i = blockIdx.x * 256 + threadIdx.x;
    float4 v = *(const float4*)(src + (size_t)i * 4);
    ushort4 o;
    o.x = f2bf(v.x); o.y = f2bf(v.y); o.z = f2bf(v.z); o.w = f2bf(v.w);
    *(ushort4*)(dst + (size_t)i * 4) = o;
    if (blockIdx.x == 0) {
        b_qkvc[l * 1536 + part * 512 + threadIdx.x * 2]     = bsrc[threadIdx.x * 2];
        b_qkvc[l * 1536 + part * 512 + threadIdx.x * 2 + 1] = bsrc[threadIdx.x * 2 + 1];
    }
}

// ---------------------------------------------------------------------------
// Staging via global_load_lds, pre-swizzled source (G21). Validated round 8.
// ---------------------------------------------------------------------------
template<int ISSUES>
static __device__ __forceinline__ void stage_tile(
    const unsigned short* __restrict__ src, int ld,
    unsigned short* lds, int wave, int lane)
{
    const int rl  = lane >> 3;
    const int sw8 = (((lane & 7) ^ rl) << 3);
#pragma unroll
    for (int i = 0; i < ISSUES; ++i) {
        const int rbase = i * 32 + wave * 8;
        const unsigned short* g = src + (size_t)(rbase + rl) * ld + sw8;
        unsigned short* l = lds + rbase * 64;
        __builtin_amdgcn_global_load_lds(
            (const __attribute__((address_space(1))) void*)g,
            (__attribute__((address_space(3))) void*)l, 16, 0, 0);
    }
}

// ---------------------------------------------------------------------------
// Unified MFMA bf16 NT GEMM. MODE 0: row=by, col=bx. MODE 2: 4096-block 1-D
// XCD-aligned decode (validated round 10: phi2 FETCH 500->83 MB).
// TRANSV: QKV V-region blocks (col0>=1024) write C transposed to vT.
// DBUF (round 13): double-buffered K-loop — prefetch tile k+1 via
// global_load_lds BEFORE computing tile k; ONE barrier per K-step (the
// barrier's vmcnt(0) drain IS the prefetch wait). For the low-occupancy
// transformer GEMMs (0.5-2 blocks/CU) where staging latency is exposed;
// phi (16 blocks/CU) keeps the validated single-buffer path.
// ---------------------------------------------------------------------------
template<int BM, int BN, int MODE, bool OUTF32, bool BIAS, bool RELU, bool POOL,
         bool RESID, bool TRANSV, bool DBUF>
__global__ __launch_bounds__(256) void mfma_nt(
    const unsigned short* __restrict__ A, long long aBatch, int lda,
    const unsigned short* __restrict__ W, long long bBatch, int ldb,
    const float* __restrict__ bias,
    const float* __restrict__ resid, int ldr,
    void* __restrict__ Cout, long long cBatch, int ldc,
    int K, float alpha, unsigned short* __restrict__ vTout)
{
    constexpr int BK = 64;
    constexpr int MI = BM / 32, NJ = BN / 32;
    __shared__ unsigned short Asl[(DBUF ? 2 : 1) * BM * BK];
    __shared__ unsigned short Bsl[(DBUF ? 2 : 1) * BN * BK];

    const int tid  = threadIdx.x;
    const int wave = tid >> 6, lane = tid & 63;
    const int wm = wave >> 1, wn = wave & 1;
    int row0, col0;
    if (MODE == 2) {
        const int f = blockIdx.x;
        const int lo = f & 7, mid = (f >> 3) & 7, hi = f >> 6;
        row0 = (hi * 8 + lo) * BM;
        col0 = mid * BN;
    } else {
        row0 = blockIdx.y * BM;
        col0 = blockIdx.x * BN;
    }
    const long long bz = blockIdx.z;
    A += bz * aBatch + (size_t)row0 * lda;
    W += bz * bBatch + (size_t)col0 * ldb;

    f32x4 acc[MI][NJ];
#pragma unroll
    for (int i = 0; i < MI; ++i)
#pragma unroll
        for (int j = 0; j < NJ; ++j) acc[i][j] = (f32x4){0.f, 0.f, 0.f, 0.f};

    if (DBUF) {
        stage_tile<MI>(A, lda, Asl, wave, lane);
        stage_tile<NJ>(W, ldb, Bsl, wave, lane);
        __syncthreads();
    }
    int cur = 0;
    for (int k0 = 0; k0 < K; k0 += BK) {
        const unsigned short *Ac, *Bc;
        if (DBUF) {
            if (k0 + BK < K) {
                stage_tile<MI>(A + k0 + BK, lda, Asl + (cur ^ 1) * BM * BK, wave, lane);
                stage_tile<NJ>(W + k0 + BK, ldb, Bsl + (cur ^ 1) * BN * BK, wave, lane);
            }
            Ac = Asl + cur * BM * BK;
            Bc = Bsl + cur * BN * BK;
        } else {
            stage_tile<MI>(A + k0, lda, Asl, wave, lane);
            stage_tile<NJ>(W + k0, ldb, Bsl, wave, lane);
            __syncthreads();
            Ac = Asl; Bc = Bsl;
        }
#pragma unroll
        for (int ks = 0; ks < 2; ++ks) {
            short8 a[MI], b[NJ];
            const int kbase = ks * 64 + (lane >> 4) * 16;
#pragma unroll
            for (int i = 0; i < MI; ++i) {
                const int ra = wm * (BM / 2) + i * 16 + (lane & 15);
                a[i] = *(const short8*)((const char*)Ac + ra * 128 + (kbase ^ ((ra & 7) << 4)));
            }
#pragma unroll
            for (int j = 0; j < NJ; ++j) {
                const int rb = wn * (BN / 2) + j * 16 + (lane & 15);
                b[j] = *(const short8*)((const char*)Bc + rb * 128 + (kbase ^ ((rb & 7) << 4)));
            }
#pragma unroll
            for (int i = 0; i < MI; ++i)
#pragma unroll
                for (int j = 0; j < NJ; ++j)
                    acc[i][j] = __builtin_amdgcn_mfma_f32_16x16x32_bf16(
                        a[i], b[j], acc[i][j], 0, 0, 0);
        }
        __syncthreads();
        cur ^= 1;
    }

    if (POOL) {
        float* red = (float*)Asl;
        red[tid] = 0.f;
        __syncthreads();
#pragma unroll
        for (int j = 0; j < NJ; ++j) {
            const int c = wn * (BN / 2) + j * 16 + (lane & 15);
            const float bi = BIAS ? bias[col0 + c] : 0.f;
            float s = 0.f;
#pragma unroll
            for (int i = 0; i < MI; ++i) {
                f32x4 v = acc[i][j];
#pragma unroll
                for (int r2 = 0; r2 < 4; ++r2) {
                    float val = v[r2] * alpha + bi;
                    if (RELU) val = fmaxf(val, 0.f);
                    s += val;
                }
            }
            atomicAdd(&red[wm * BN + c], s);
        }
        __syncthreads();
        float* C = (float*)Cout + bz * cBatch;
        const int pm = tid >> 7, c = tid & 127;
        C[(size_t)(row0 / 64 + pm) * ldc + col0 + c] = red[pm * BN + c];
    } else if (TRANSV && col0 >= 1024) {
        // V region of the fused QKV: write C transposed to vT via LDS bounce.
        unsigned short* tr = Asl;   // 64x64 ushort = 8 KB (dead LDS)
#pragma unroll
        for (int i = 0; i < MI; ++i) {
            const int rr = wm * (BM / 2) + i * 16 + (lane >> 4) * 4;
#pragma unroll
            for (int j = 0; j < NJ; ++j) {
                const int c = wn * (BN / 2) + j * 16 + (lane & 15);
                const float bi = BIAS ? bias[col0 + c] : 0.f;
                f32x4 v = acc[i][j];
#pragma unroll
                for (int r2 = 0; r2 < 4; ++r2)
                    tr[(rr + r2) * BN + c] = f2bf(v[r2] * alpha + bi);
            }
        }
        __syncthreads();
        const int c  = tid >> 2;
        const int r4 = (tid & 3) * 16;
        ushort4 o[4];
#pragma unroll
        for (int e = 0; e < 16; ++e)
            ((unsigned short*)o)[e] = tr[(r4 + e) * BN + c];
        unsigned short* dst = vTout + (size_t)(col0 - 1024 + c) * 1024 + row0 + r4;
        *(ushort4*)(dst + 0)  = o[0];
        *(ushort4*)(dst + 4)  = o[1];
        *(ushort4*)(dst + 8)  = o[2];
        *(ushort4*)(dst + 12) = o[3];
    } else {
        float* Cf = (float*)Cout + (OUTF32 ? bz * cBatch : 0);
        unsigned short* Cu = (unsigned short*)Cout + (OUTF32 ? 0 : bz * cBatch);
#pragma unroll
        for (int i = 0; i < MI; ++i) {
            const int rg = row0 + wm * (BM / 2) + i * 16 + (lane >> 4) * 4;
#pragma unroll
            for (int j = 0; j < NJ; ++j) {
                const int c = col0 + wn * (BN / 2) + j * 16 + (lane & 15);
                const float bi = BIAS ? bias[c] : 0.f;
                f32x4 v = acc[i][j];
#pragma unroll
                for (int r2 = 0; r2 < 4; ++r2) {
                    float val = v[r2] * alpha + bi;
                    if (RELU) val = fmaxf(val, 0.f);
                    if (RESID) val += resid[(size_t)(rg + r2) * ldr + c];
                    if (OUTF32) Cf[(size_t)(rg + r2) * ldc + c] = val;
                    else        Cu[(size_t)(rg + r2) * ldc + c] = f2bf(val);
                }
            }
        }
    }
}

// ---------------------------------------------------------------------------
// Fused flash attention, round-13 double-buffered: K and V tiles for kt+1 are
// prefetched at the TOP of iteration kt (overlapping the whole S/softmax/PV
// phase); ONE barrier per iteration (was 2). Ps write->read is wave-local
// (each wave's 16-row stripe) so needs no barrier — compiler lgkm ordering
// suffices. LDS 40 KB.
// ---------------------------------------------------------------------------
__global__ __launch_bounds__(256) void flash_attn(
    const unsigned short* __restrict__ qkv,   // [1024][1536] (q|k|v)
    const unsigned short* __restrict__ vT,    // [512][1024]
    unsigned short* __restrict__ O)           // [1024][512]
{
    __shared__ unsigned short Qs[64 * 64];
    __shared__ unsigned short Ks[2][64 * 64];
    __shared__ unsigned short Vs[2][64 * 64];
    __shared__ unsigned short Ps[64 * 64];

    const int tid = threadIdx.x, wave = tid >> 6, lane = tid & 63;
    const int q0 = blockIdx.x * 64;
    const int h  = blockIdx.y;

    stage_tile<2>(qkv + (size_t)q0 * 1536 + h * 64, 1536, Qs, wave, lane);
    stage_tile<2>(qkv + 512 + h * 64, 1536, Ks[0], wave, lane);
    stage_tile<2>(vT + (size_t)(h * 64) * 1024, 1024, Vs[0], wave, lane);
    __syncthreads();

    f32x4 Oacc[4];
#pragma unroll
    for (int j = 0; j < 4; ++j) Oacc[j] = (f32x4){0.f, 0.f, 0.f, 0.f};
    float mrow[4] = {-1e30f, -1e30f, -1e30f, -1e30f};
    float lrow[4] = {0.f, 0.f, 0.f, 0.f};

    for (int kt = 0; kt < 16; ++kt) {
        if (kt < 15) {   // prefetch next K/V into the other buffer
            stage_tile<2>(qkv + 512 + (size_t)((kt + 1) * 64) * 1536 + h * 64, 1536,
                          Ks[(kt + 1) & 1], wave, lane);
            stage_tile<2>(vT + (size_t)(h * 64) * 1024 + (kt + 1) * 64, 1024,
                          Vs[(kt + 1) & 1], wave, lane);
        }
        const unsigned short* Kc = Ks[kt & 1];
        const unsigned short* Vc = Vs[kt & 1];

        f32x4 s[4];
#pragma unroll
        for (int j = 0; j < 4; ++j) s[j] = (f32x4){0.f, 0.f, 0.f, 0.f};
#pragma unroll
        for (int ks = 0; ks < 2; ++ks) {
            const int kbase = ks * 64 + (lane >> 4) * 16;
            const int ra = wave * 16 + (lane & 15);
            short8 aq = *(const short8*)((const char*)Qs + ra * 128 + (kbase ^ ((ra & 7) << 4)));
#pragma unroll
            for (int j = 0; j < 4; ++j) {
                const int rb = j * 16 + (lane & 15);
                short8 bk8 = *(const short8*)((const char*)Kc + rb * 128 + (kbase ^ ((rb & 7) << 4)));
                s[j] = __builtin_amdgcn_mfma_f32_16x16x32_bf16(aq, bk8, s[j], 0, 0, 0);
            }
        }

        float f[4];
#pragma unroll
        for (int r = 0; r < 4; ++r) {
            float mx = -1e30f;
#pragma unroll
            for (int j = 0; j < 4; ++j) { s[j][r] *= 0.125f; mx = fmaxf(mx, s[j][r]); }
#pragma unroll
            for (int o = 1; o < 16; o <<= 1) mx = fmaxf(mx, __shfl_xor(mx, o));
            const float mn = fmaxf(mrow[r], mx);
            f[r] = expf(mrow[r] - mn);
            mrow[r] = mn;
            float sm = 0.f;
#pragma unroll
            for (int j = 0; j < 4; ++j) { s[j][r] = expf(s[j][r] - mn); sm += s[j][r]; }
#pragma unroll
            for (int o = 1; o < 16; o <<= 1) sm += __shfl_xor(sm, o);
            lrow[r] = lrow[r] * f[r] + sm;
        }
#pragma unroll
        for (int j = 0; j < 4; ++j)
#pragma unroll
            for (int r = 0; r < 4; ++r) Oacc[j][r] *= f[r];

        // P (C-layout) -> LDS (swizzled); wave-local stripe, no barrier needed
#pragma unroll
        for (int j = 0; j < 4; ++j) {
            const int col = (lane & 15) + j * 16;
#pragma unroll
            for (int r = 0; r < 4; ++r) {
                const int row = wave * 16 + (lane >> 4) * 4 + r;
                *(unsigned short*)((char*)Ps + row * 128 + ((col * 2) ^ ((row & 7) << 4))) =
                    f2bf(s[j][r]);
            }
        }

#pragma unroll
        for (int ks = 0; ks < 2; ++ks) {
            const int kbase = ks * 64 + (lane >> 4) * 16;
            const int ra = wave * 16 + (lane & 15);
            short8 ap = *(const short8*)((const char*)Ps + ra * 128 + (kbase ^ ((ra & 7) << 4)));
#pragma unroll
            for (int j = 0; j < 4; ++j) {
                const int rb = j * 16 + (lane & 15);
                short8 bv8 = *(const short8*)((const char*)Vc + rb * 128 + (kbase ^ ((rb & 7) << 4)));
                Oacc[j] = __builtin_amdgcn_mfma_f32_16x16x32_bf16(ap, bv8, Oacc[j], 0, 0, 0);
            }
        }
        __syncthreads();   // drains prefetch (vmcnt0) + publishes next K/V
    }

    float linv[4];
#pragma unroll
    for (int r = 0; r < 4; ++r) linv[r] = 1.0f / lrow[r];
#pragma unroll
    for (int j = 0; j < 4; ++j) {
        const int c = h * 64 + j * 16 + (lane & 15);
#pragma unroll
        for (int r = 0; r < 4; ++r) {
            const int row = q0 + wave * 16 + (lane >> 4) * 4 + r;
            O[(size_t)row * D_ + c] = f2bf(Oacc[j][r] * linv[r]);
        }
    }
}

// ---------------------------------------------------------------------------
// LayerNorm over 512 elems, dual output (fp32 x + bf16 xb). One wave per row.
// ---------------------------------------------------------------------------
__global__ __launch_bounds__(64) void ln_kernel(
    const float* __restrict__ y, const float* __restrict__ w,
    const float* __restrict__ b, float* __restrict__ x,
    unsigned short* __restrict__ xb)
{
    const int row = blockIdx.x;
    const int lane = threadIdx.x;
    const float* yr = y + (long long)row * 512;
    float4 v0 = *(const float4*)(yr + lane * 8);
    float4 v1 = *(const float4*)(yr + lane * 8 + 4);
    float vals[8] = {v0.x, v0.y, v0.z, v0.w, v1.x, v1.y, v1.z, v1.w};
    float s = 0.f;
#pragma unroll
    for (int j = 0; j < 8; ++j) s += vals[j];
#pragma unroll
    for (int o = 32; o >= 1; o >>= 1) s += __shfl_xor(s, o);
    const float mu = s * (1.f / 512.f);
    float q = 0.f;
#pragma unroll
    for (int j = 0; j < 8; ++j) { float d = vals[j] - mu; q += d * d; }
#pragma unroll
    for (int o = 32; o >= 1; o >>= 1) q += __shfl_xor(q, o);
    const float inv = 1.0f / sqrtf(q * (1.f / 512.f) + EPS_);
    float ov[8];
#pragma unroll
    for (int j = 0; j < 8; ++j)
        ov[j] = (vals[j] - mu) * inv * w[lane * 8 + j] + b[lane * 8 + j];
    float4 o0 = {ov[0], ov[1], ov[2], ov[3]};
    float4 o1 = {ov[4], ov[5], ov[6], ov[7]};
    *(float4*)(x + (long long)row * 512 + lane * 8) = o0;
    *(float4*)(x + (long long)row * 512 + lane * 8 + 4) = o1;
    ushort4 u0, u1;
    u0.x = f2bf(ov[0]); u0.y = f2bf(ov[1]); u0.z = f2bf(ov[2]); u0.w = f2bf(ov[3]);
    u1.x = f2bf(ov[4]); u1.y = f2bf(ov[5]); u1.z = f2bf(ov[6]); u1.w = f2bf(ov[7]);
    *(ushort4*)(xb + (long long)row * 512 + lane * 8) = u0;
    *(ushort4*)(xb + (long long)row * 512 + lane * 8 + 4) = u1;
}

// ---------------------------------------------------------------------------
// LN over y = sum of 4 split-K partials + bias + resid (round-13 ffn2 split).
// ---------------------------------------------------------------------------
__global__ __launch_bounds__(64) void ln_sum4_kernel(
    const float* __restrict__ y4,     // [4][1024][512]
    const float* __restrict__ bias,   // [512]
    const float* __restrict__ w, const float* __restrict__ b,
    float* __restrict__ x, unsigned short* __restrict__ xb)
{
    const int row = blockIdx.x;
    const int lane = threadIdx.x;
    const size_t off = (size_t)row * 512 + lane * 8;
    float vals[8];
#pragma unroll
    for (int j = 0; j < 8; ++j) vals[j] = x[off + j] + bias[lane * 8 + j];
#pragma unroll
    for (int z = 0; z < 4; ++z) {
        float4 p0 = *(const float4*)(y4 + (size_t)z * 524288 + off);
        float4 p1 = *(const float4*)(y4 + (size_t)z * 524288 + off + 4);
        vals[0] += p0.x; vals[1] += p0.y; vals[2] += p0.z; vals[3] += p0.w;
        vals[4] += p1.x; vals[5] += p1.y; vals[6] += p1.z; vals[7] += p1.w;
    }
    float s = 0.f;
#pragma unroll
    for (int j = 0; j < 8; ++j) s += vals[j];
#pragma unroll
    for (int o = 32; o >= 1; o >>= 1) s += __shfl_xor(s, o);
    const float mu = s * (1.f / 512.f);
    float q = 0.f;
#pragma unroll
    for (int j = 0; j < 8; ++j) { float d = vals[j] - mu; q += d * d; }
#pragma unroll
    for (int o = 32; o >= 1; o >>= 1) q += __shfl_xor(q, o);
    const float inv = 1.0f / sqrtf(q * (1.f / 512.f) + EPS_);
    float ov[8];
#pragma unroll
    for (int j = 0; j < 8; ++j)
        ov[j] = (vals[j] - mu) * inv * w[lane * 8 + j] + b[lane * 8 + j];
    float4 o0 = {ov[0], ov[1], ov[2], ov[3]};
    float4 o1 = {ov[4], ov[5], ov[6], ov[7]};
    *(float4*)(x + off) = o0;
    *(float4*)(x + off + 4) = o1;
    ushort4 u0, u1;
    u0.x = f2bf(ov[0]); u0.y = f2bf(ov[1]); u0.z = f2bf(ov[2]); u0.w = f2bf(ov[3]);
    u1.x = f2bf(ov[4]); u1.y = f2bf(ov[5]); u1.z = f2bf(ov[6]); u1.w = f2bf(ov[7]);
    *(ushort4*)(xb + off) = u0;
    *(ushort4*)(xb + off + 4) = u1;
}

// ---------------------------------------------------------------------------
// Output fill: 0xFBFF finite under bf16/fp16/fp32 views (rounds 0-3 lesson).
// ---------------------------------------------------------------------------
__global__ __launch_bounds__(256) void fill_sentinel_bf16(unsigned short* __restrict__ out)
{
    const long long i = (long long)blockIdx.x * blockDim.x + threadIdx.x;
    const unsigned int pat = 0xFBFFFBFFu;
    uint4 v = {pat, pat, pat, pat};
    *(uint4*)(out + i * 8) = v;
}

// ---------------------------------------------------------------------------
// Fused values+scatter: compute only the 2048 selected (r,c) dot products.
// ---------------------------------------------------------------------------
__global__ __launch_bounds__(256) void scatter_dot(
    const int* __restrict__ rows, const int* __restrict__ cols,
    const unsigned short* __restrict__ xb, __hip_bfloat16* __restrict__ out)
{
    const int k = blockIdx.x * 4 + (threadIdx.x >> 6);
    const int lane = threadIdx.x & 63;
    const int r = rows[k], c = cols[k];
    const unsigned short* xr = xb + (size_t)r * 512 + lane * 8;
    const unsigned short* xc = xb + (size_t)c * 512 + lane * 8;
    ushort4 a0 = *(const ushort4*)xr, a1 = *(const ushort4*)(xr + 4);
    ushort4 b0 = *(const ushort4*)xc, b1 = *(const ushort4*)(xc + 4);
    float s = bf2f(a0.x) * bf2f(b0.x) + bf2f(a0.y) * bf2f(b0.y) +
              bf2f(a0.z) * bf2f(b0.z) + bf2f(a0.w) * bf2f(b0.w) +
              bf2f(a1.x) * bf2f(b1.x) + bf2f(a1.y) * bf2f(b1.y) +
              bf2f(a1.z) * bf2f(b1.z) + bf2f(a1.w) * bf2f(b1.w);
#pragma unroll
    for (int o = 32; o >= 1; o >>= 1) s += __shfl_xor(s, o);
    if (lane == 0) {
        if (!(fabsf(s) < 1e30f)) s = 0.f;
        out[(size_t)r * 1024 + c] = __float2bfloat16(s);
    }
}

// ---------------------------------------------------------------------------
extern "C" void kernel_launch(void* const* d_in, const int* in_sizes, int n_in,
                              void* d_out, int out_size, void* d_ws, size_t ws_size,
                              hipStream_t stream)
{
    const float* ideal  = (const float*)d_in[0];
    const int*   rows   = (const int*)d_in[1];
    const int*   cols   = (const int*)d_in[2];
    const float* Wm     = (const float*)d_in[3];
    const float* bm     = (const float*)d_in[4];
    const float* Wphi1  = (const float*)d_in[5];
    const float* bphi1  = (const float*)d_in[6];
    const float* Wphi2  = (const float*)d_in[7];
    const float* bphi2  = (const float*)d_in[8];
    const float* Wrho1  = (const float*)d_in[9];
    const float* brho1  = (const float*)d_in[10];
    const float* Wrho2  = (const float*)d_in[11];
    const float* brho2  = (const float*)d_in[12];
    const float* Wq     = (const float*)d_in[13];
    const float* bq     = (const float*)d_in[14];
    const float* Wk     = (const float*)d_in[15];
    const float* bk     = (const float*)d_in[16];
    const float* Wv     = (const float*)d_in[17];
    const float* bv     = (const float*)d_in[18];
    const float* Wo     = (const float*)d_in[19];
    const float* bo     = (const float*)d_in[20];
    const float* ln1w   = (const float*)d_in[21];
    const float* ln1b   = (const float*)d_in[22];
    const float* W1     = (const float*)d_in[23];
    const float* b1     = (const float*)d_in[24];
    const float* W2     = (const float*)d_in[25];
    const float* b2     = (const float*)d_in[26];
    const float* ln2w   = (const float*)d_in[27];
    const float* ln2b   = (const float*)d_in[28];
    __hip_bfloat16* out = (__hip_bfloat16*)d_out;

    // ---- Workspace (MB offsets; ws_size = 256 MiB, round-6 evidence) ----
    char* base = (char*)d_ws;
    unsigned short* w_phi1 = (unsigned short*)(base + (0ll  << 20));
    unsigned short* w_phi2 = (unsigned short*)(base + (1ll  << 20));
    unsigned short* w_rho1 = (unsigned short*)(base + (3ll  << 20));
    unsigned short* w_rho2 = (unsigned short*)(base + (5ll  << 20));
    unsigned short* w_qkv  = (unsigned short*)(base + (6ll  << 20));  // 4 x 1.5MB
    unsigned short* w_o    = (unsigned short*)(base + (12ll << 20));  // 2MB
    unsigned short* w_1    = (unsigned short*)(base + (14ll << 20));  // 8MB
    unsigned short* w_2    = (unsigned short*)(base + (22ll << 20));  // 8MB
    float*          b_qkvc = (float*)         (base + (30ll << 20));  // 24KB
    unsigned short* h0b    = (unsigned short*)(base + (31ll << 20));  // 64MB
    unsigned short* h1b    = (unsigned short*)(base + (95ll << 20));  // 128MB
    float*          sbuf   = (float*)         (base + (223ll << 20)); // 4MB
    unsigned short* id_pad = (unsigned short*)(base + (227ll << 20)); // 8MB
    unsigned short* wm_pad = (unsigned short*)(base + (236ll << 20)); // 64KB
    unsigned short* sb_b   = (unsigned short*)(base + (31ll << 20));
    unsigned short* tb_b   = (unsigned short*)(base + (33ll << 20));
    float*          xbuf   = (float*)         (base + (35ll << 20));
    unsigned short* xb     = (unsigned short*)(base + (37ll << 20));
    float*          ybuf   = (float*)         (base + (38ll << 20));
    unsigned short* qkvb   = (unsigned short*)(base + (40ll << 20));  // [1024][1536]
    unsigned short* vT     = (unsigned short*)(base + (43ll << 20));
    unsigned short* ob     = (unsigned short*)(base + (44ll << 20));
    unsigned short* ffnt   = (unsigned short*)(base + (45ll << 20));  // 4MB
    float*          ysplit = (float*)         (base + (49ll << 20));  // 8MB

    // ---------------- Output fill first (independent) --------
    fill_sentinel_bf16<<<512, 256, 0, stream>>>((unsigned short*)out);

    // ---------------- Weight conversion ----------------
    cvt_all<<<12288, 256, 0, stream>>>(Wphi1, Wphi2, Wrho1, Wrho2, Wo, W1, W2,
                                       w_phi1, w_phi2, w_rho1, w_rho2, w_o, w_1, w_2);
    cvt_qkv_kernel<<<dim3(256, 3, NL), 256, 0, stream>>>(Wq, Wk, Wv, bq, bk, bv,
                                                          w_qkv, b_qkvc);
    cvt_pad64<<<2048, 256, 0, stream>>>(ideal, id_pad, NP * NM);
    cvt_pad64<<<16, 256, 0, stream>>>(Wm, wm_pad, D_);

    // ---------------- DeepSets ----------------
    // embed as K=64 MFMA GEMM
    mfma_nt<128, 128, 0, false, true, true, false, false, false, false><<<dim3(4, 512), 256, 0, stream>>>(
        id_pad, 0, 64, wm_pad, 0, 64, bm, nullptr, 0, h0b, 0, D_, 64, 1.0f, nullptr);
    // phi1 (MODE 2, single-buffer — validated path, 16 blocks/CU)
    mfma_nt<128, 128, 2, false, true, true, false, false, false, false><<<4096, 256, 0, stream>>>(
        h0b, 0, D_, w_phi1, 0, D_, bphi1, nullptr, 0, h1b, 0, HID_, D_, 1.0f, nullptr);
    // phi2+pool (MODE 2)
    mfma_nt<128, 128, 2, true, true, true, true, false, false, false><<<4096, 256, 0, stream>>>(
        h1b, 0, HID_, w_phi2, 0, HID_, bphi2, nullptr, 0, sbuf, 0, HID_, HID_, 1.0f, nullptr);

    // rho (64^2 tiles, DBUF)
    cvt_bf16_kernel<<<1024, 256, 0, stream>>>(sbuf, sb_b, 262144);
    mfma_nt<64, 64, 0, false, true, true, false, false, false, true><<<dim3(16, 16), 256, 0, stream>>>(
        sb_b, 0, HID_, w_rho1, 0, HID_, brho1, nullptr, 0, tb_b, 0, HID_, HID_, 1.0f, nullptr);
    mfma_nt<64, 64, 0, true, true, true, false, false, false, true><<<dim3(8, 16), 256, 0, stream>>>(
        tb_b, 0, HID_, w_rho2, 0, HID_, brho2, nullptr, 0, xbuf, 0, D_, HID_, 1.0f, nullptr);
    cvt_bf16_kernel<<<512, 256, 0, stream>>>(xbuf, xb, 131072);

    // ---------------- Transformer (DBUF everywhere, ffn2 split-K=4) --------
    for (int l = 0; l < NL; ++l) {
        // QKV fused (TRANSV writes vT for V-region blocks)
        mfma_nt<64, 64, 0, false, true, false, false, false, true, true><<<dim3(24, 16), 256, 0, stream>>>(
            xb, 0, D_, w_qkv + (long long)l * 1536 * D_, 0, D_, b_qkvc + l * 1536,
            nullptr, 0, qkvb, 0, 1536, D_, 1.0f, vT);
        // fused scores+softmax+PV (double-buffered K/V)
        flash_attn<<<dim3(16, NH), 256, 0, stream>>>(qkvb, vT, ob);
        // y = ob @ Wo^T + bo + x  (f32)
        mfma_nt<64, 64, 0, true, true, false, false, true, false, true><<<dim3(8, 16), 256, 0, stream>>>(
            ob, 0, D_, w_o + (long long)l * D_ * D_, 0, D_, bo + l * D_,
            xbuf, D_, ybuf, 0, D_, D_, 1.0f, nullptr);
        ln_kernel<<<NP, 64, 0, stream>>>(ybuf, ln1w + l * D_, ln1b + l * D_, xbuf, xb);
        // ffn1: xb @ W1^T + b1, relu -> bf16
        mfma_nt<64, 64, 0, false, true, true, false, false, false, true><<<dim3(32, 16), 256, 0, stream>>>(
            xb, 0, D_, w_1 + (long long)l * FF_ * D_, 0, D_, b1 + l * FF_,
            nullptr, 0, ffnt, 0, FF_, D_, 1.0f, nullptr);
        // ffn2 split-K=4: z-th block pair computes K range [z*512, z*512+512)
        // into ysplit[z] (pure f32 partial, no bias/resid); ln_sum4 folds them.
        mfma_nt<64, 64, 0, true, false, false, false, false, false, true><<<dim3(8, 16, 4), 256, 0, stream>>>(
            ffnt, 512, FF_, w_2 + (long long)l * D_ * FF_, 512, FF_, nullptr,
            nullptr, 0, ysplit, 524288, D_, 512, 1.0f, nullptr);
        ln_sum4_kernel<<<NP, 64, 0, stream>>>(ysplit, b2 + l * D_,
                                              ln2w + l * D_, ln2b + l * D_, xbuf, xb);
    }

    // scatter: out[r,c] = dot(x[r], x[c]) for the 2048 selected pairs only
    scatter_dot<<<NK / 4, 256, 0, stream>>>(rows, cols, xb, out);
}

// Round 14
// 573.799 us; speedup vs baseline: 1.7701x; 1.1263x over previous
//
#include <hip/hip_runtime.h>
#include <hip/hip_bf16.h>

// Problem constants
#define NP    1024   // polynomials
#define NM    64     // monomials per poly
#define MD_   16
#define D_    512
#define NH    8
#define DH_   64
#define NL    4
#define FF_   2048
#define HID_  1024
#define NK    2048
#define EPS_  1e-5f

typedef __attribute__((ext_vector_type(8))) short short8;
typedef __attribute__((ext_vector_type(4))) float f32x4;

static __device__ __forceinline__ unsigned short f2bf(float f) {
    __hip_bfloat16 h = __float2bfloat16(f);
    return *reinterpret_cast<unsigned short*>(&h);
}
static __device__ __forceinline__ float bf2f(unsigned short u) {
    unsigned int x = ((unsigned int)u) << 16;
    return __uint_as_float(x);
}

// ---------------------------------------------------------------------------
// MEGA conversion kernel (round 14): output sentinel fill + all weight
// converts + QKV pack + bias gather + K=64 pads in ONE launch (was 5+).
// Segments by blockIdx.x range. 17936 blocks total.
// ---------------------------------------------------------------------------
__global__ __launch_bounds__(256) void mega_cvt(
    const float* __restrict__ Wphi1, const float* __restrict__ Wphi2,
    const float* __restrict__ Wrho1, const float* __restrict__ Wrho2,
    const float* __restrict__ Wo,    const float* __restrict__ W1,
    const float* __restrict__ W2,
    unsigned short* __restrict__ w_phi1, unsigned short* __restrict__ w_phi2,
    unsigned short* __restrict__ w_rho1, unsigned short* __restrict__ w_rho2,
    unsigned short* __restrict__ w_o,    unsigned short* __restrict__ w_1,
    unsigned short* __restrict__ w_2,
    const float* __restrict__ Wq, const float* __restrict__ Wk,
    const float* __restrict__ Wv, const float* __restrict__ bq,
    const float* __restrict__ bk, const float* __restrict__ bv,
    unsigned short* __restrict__ w_qkv, float* __restrict__ b_qkvc,
    const float* __restrict__ ideal, unsigned short* __restrict__ id_pad,
    const float* __restrict__ Wm,    unsigned short* __restrict__ wm_pad,
    unsigned short* __restrict__ out)
{
    const int b = blockIdx.x, t = threadIdx.x;
    if (b < 512) {
        // output sentinel: 0xFBFF finite under bf16/fp16/fp32 views (r0-3 lesson)
        const long long i = (long long)b * 256 + t;
        const unsigned int pat = 0xFBFFFBFFu;
        uint4 v = {pat, pat, pat, pat};
        *(uint4*)(out + i * 8) = v;
    } else if (b < 12800) {
        const int i = (b - 512) * 256 + t;   // f4 index < 3145728
        const float* src; unsigned short* dst; int l;
        if      (i <  131072) { src = Wphi1; dst = w_phi1; l = i; }
        else if (i <  393216) { src = Wphi2; dst = w_phi2; l = i -  131072; }
        else if (i <  655360) { src = Wrho1; dst = w_rho1; l = i -  393216; }
        else if (i <  786432) { src = Wrho2; dst = w_rho2; l = i -  655360; }
        else if (i < 1048576) { src = Wo;    dst = w_o;    l = i -  786432; }
        else if (i < 2097152) { src = W1;    dst = w_1;    l = i - 1048576; }
        else                  { src = W2;    dst = w_2;    l = i - 2097152; }
        float4 v = *(const float4*)(src + (size_t)l * 4);
        ushort4 o;
        o.x = f2bf(v.x); o.y = f2bf(v.y); o.z = f2bf(v.z); o.w = f2bf(v.w);
        *(ushort4*)(dst + (size_t)l * 4) = o;
    } else if (b < 15872) {
        const int g = (b - 12800) >> 8;      // 0..11
        const int inner = (b - 12800) & 255;
        const int part = g % 3, l = g / 3;
        const float* src  = (part == 0 ? Wq : part == 1 ? Wk : Wv) + (size_t)l * D_ * D_;
        const float* bsrc = (part == 0 ? bq : part == 1 ? bk : bv) + l * D_;
        unsigned short* dst = w_qkv + (size_t)l * 1536 * D_ + (size_t)part * 512 * D_;
        const int i = inner * 256 + t;       // f4 index < 65536
        float4 v = *(const float4*)(src + (size_t)i * 4);
        ushort4 o;
        o.x = f2bf(v.x); o.y = f2bf(v.y); o.z = f2bf(v.z); o.w = f2bf(v.w);
        *(ushort4*)(dst + (size_t)i * 4) = o;
        if (inner == 0) {
            b_qkvc[l * 1536 + part * 512 + t * 2]     = bsrc[t * 2];
            b_qkvc[l * 1536 + part * 512 + t * 2 + 1] = bsrc[t * 2 + 1];
        }
    } else {
        // pad-convert [nrows][16] f32 -> [nrows][64] bf16 (cols 16..63 = 0)
        const float* src; unsigned short* dst; int row;
        if (b < 17920) { src = ideal; dst = id_pad; row = (b - 15872) * 32 + (t >> 3); }
        else           { src = Wm;    dst = wm_pad; row = (b - 17920) * 32 + (t >> 3); }
        const int c8 = (t & 7) * 8;
        ushort4 o0 = {0, 0, 0, 0}, o1 = {0, 0, 0, 0};
        if (c8 < 16) {
            float4 a = *(const float4*)(src + (size_t)row * 16 + c8);
            float4 bb = *(const float4*)(src + (size_t)row * 16 + c8 + 4);
            o0.x = f2bf(a.x);  o0.y = f2bf(a.y);  o0.z = f2bf(a.z);  o0.w = f2bf(a.w);
            o1.x = f2bf(bb.x); o1.y = f2bf(bb.y); o1.z = f2bf(bb.z); o1.w = f2bf(bb.w);
        }
        *(ushort4*)(dst + (size_t)row * 64 + c8) = o0;
        *(ushort4*)(dst + (size_t)row * 64 + c8 + 4) = o1;
    }
}

__global__ __launch_bounds__(256) void cvt_bf16_kernel(
    const float* __restrict__ in, unsigned short* __restrict__ out, int n4)
{
    const int i = blockIdx.x * 256 + threadIdx.x;
    if (i < n4) {
        float4 v = *(const float4*)(in + (size_t)i * 4);
        ushort4 o;
        o.x = f2bf(v.x); o.y = f2bf(v.y); o.z = f2bf(v.z); o.w = f2bf(v.w);
        *(ushort4*)(out + (size_t)i * 4) = o;
    }
}

// ---------------------------------------------------------------------------
// Staging via global_load_lds, pre-swizzled source (G21). Validated round 8.
// ---------------------------------------------------------------------------
template<int ISSUES>
static __device__ __forceinline__ void stage_tile(
    const unsigned short* __restrict__ src, int ld,
    unsigned short* lds, int wave, int lane)
{
    const int rl  = lane >> 3;
    const int sw8 = (((lane & 7) ^ rl) << 3);
#pragma unroll
    for (int i = 0; i < ISSUES; ++i) {
        const int rbase = i * 32 + wave * 8;
        const unsigned short* g = src + (size_t)(rbase + rl) * ld + sw8;
        unsigned short* l = lds + rbase * 64;
        __builtin_amdgcn_global_load_lds(
            (const __attribute__((address_space(1))) void*)g,
            (__attribute__((address_space(3))) void*)l, 16, 0, 0);
    }
}

// ---------------------------------------------------------------------------
// Unified MFMA bf16 NT GEMM. MODE 0: row=by, col=bx. MODE 2: 4096-block 1-D
// XCD-aligned decode (validated r10: phi2 FETCH 500->83 MB). TRANSV: QKV
// V-region blocks write C transposed to vT. DBUF (r13): double-buffered
// K-loop, one barrier per K-step. BOTH (r14): OUTF32 epilogue also writes a
// bf16 mirror via vTout (used by rho2 -> xbuf+xb, deletes a cvt launch).
// ---------------------------------------------------------------------------
template<int BM, int BN, int MODE, bool OUTF32, bool BIAS, bool RELU, bool POOL,
         bool RESID, bool TRANSV, bool DBUF, bool BOTH>
__global__ __launch_bounds__(256) void mfma_nt(
    const unsigned short* __restrict__ A, long long aBatch, int lda,
    const unsigned short* __restrict__ W, long long bBatch, int ldb,
    const float* __restrict__ bias,
    const float* __restrict__ resid, int ldr,
    void* __restrict__ Cout, long long cBatch, int ldc,
    int K, float alpha, unsigned short* __restrict__ vTout)
{
    constexpr int BK = 64;
    constexpr int MI = BM / 32, NJ = BN / 32;
    __shared__ unsigned short Asl[(DBUF ? 2 : 1) * BM * BK];
    __shared__ unsigned short Bsl[(DBUF ? 2 : 1) * BN * BK];

    const int tid  = threadIdx.x;
    const int wave = tid >> 6, lane = tid & 63;
    const int wm = wave >> 1, wn = wave & 1;
    int row0, col0;
    if (MODE == 2) {
        const int f = blockIdx.x;
        const int lo = f & 7, mid = (f >> 3) & 7, hi = f >> 6;
        row0 = (hi * 8 + lo) * BM;
        col0 = mid * BN;
    } else {
        row0 = blockIdx.y * BM;
        col0 = blockIdx.x * BN;
    }
    const long long bz = blockIdx.z;
    A += bz * aBatch + (size_t)row0 * lda;
    W += bz * bBatch + (size_t)col0 * ldb;

    f32x4 acc[MI][NJ];
#pragma unroll
    for (int i = 0; i < MI; ++i)
#pragma unroll
        for (int j = 0; j < NJ; ++j) acc[i][j] = (f32x4){0.f, 0.f, 0.f, 0.f};

    if (DBUF) {
        stage_tile<MI>(A, lda, Asl, wave, lane);
        stage_tile<NJ>(W, ldb, Bsl, wave, lane);
        __syncthreads();
    }
    int cur = 0;
    for (int k0 = 0; k0 < K; k0 += BK) {
        const unsigned short *Ac, *Bc;
        if (DBUF) {
            if (k0 + BK < K) {
                stage_tile<MI>(A + k0 + BK, lda, Asl + (cur ^ 1) * BM * BK, wave, lane);
                stage_tile<NJ>(W + k0 + BK, ldb, Bsl + (cur ^ 1) * BN * BK, wave, lane);
            }
            Ac = Asl + cur * BM * BK;
            Bc = Bsl + cur * BN * BK;
        } else {
            stage_tile<MI>(A + k0, lda, Asl, wave, lane);
            stage_tile<NJ>(W + k0, ldb, Bsl, wave, lane);
            __syncthreads();
            Ac = Asl; Bc = Bsl;
        }
#pragma unroll
        for (int ks = 0; ks < 2; ++ks) {
            short8 a[MI], b[NJ];
            const int kbase = ks * 64 + (lane >> 4) * 16;
#pragma unroll
            for (int i = 0; i < MI; ++i) {
                const int ra = wm * (BM / 2) + i * 16 + (lane & 15);
                a[i] = *(const short8*)((const char*)Ac + ra * 128 + (kbase ^ ((ra & 7) << 4)));
            }
#pragma unroll
            for (int j = 0; j < NJ; ++j) {
                const int rb = wn * (BN / 2) + j * 16 + (lane & 15);
                b[j] = *(const short8*)((const char*)Bc + rb * 128 + (kbase ^ ((rb & 7) << 4)));
            }
#pragma unroll
            for (int i = 0; i < MI; ++i)
#pragma unroll
                for (int j = 0; j < NJ; ++j)
                    acc[i][j] = __builtin_amdgcn_mfma_f32_16x16x32_bf16(
                        a[i], b[j], acc[i][j], 0, 0, 0);
        }
        __syncthreads();
        cur ^= 1;
    }

    if (POOL) {
        float* red = (float*)Asl;
        red[tid] = 0.f;
        __syncthreads();
#pragma unroll
        for (int j = 0; j < NJ; ++j) {
            const int c = wn * (BN / 2) + j * 16 + (lane & 15);
            const float bi = BIAS ? bias[col0 + c] : 0.f;
            float s = 0.f;
#pragma unroll
            for (int i = 0; i < MI; ++i) {
                f32x4 v = acc[i][j];
#pragma unroll
                for (int r2 = 0; r2 < 4; ++r2) {
                    float val = v[r2] * alpha + bi;
                    if (RELU) val = fmaxf(val, 0.f);
                    s += val;
                }
            }
            atomicAdd(&red[wm * BN + c], s);
        }
        __syncthreads();
        float* C = (float*)Cout + bz * cBatch;
        const int pm = tid >> 7, c = tid & 127;
        C[(size_t)(row0 / 64 + pm) * ldc + col0 + c] = red[pm * BN + c];
    } else if (TRANSV && col0 >= 1024) {
        unsigned short* tr = Asl;   // 64x64 ushort (dead LDS)
#pragma unroll
        for (int i = 0; i < MI; ++i) {
            const int rr = wm * (BM / 2) + i * 16 + (lane >> 4) * 4;
#pragma unroll
            for (int j = 0; j < NJ; ++j) {
                const int c = wn * (BN / 2) + j * 16 + (lane & 15);
                const float bi = BIAS ? bias[col0 + c] : 0.f;
                f32x4 v = acc[i][j];
#pragma unroll
                for (int r2 = 0; r2 < 4; ++r2)
                    tr[(rr + r2) * BN + c] = f2bf(v[r2] * alpha + bi);
            }
        }
        __syncthreads();
        const int c  = tid >> 2;
        const int r4 = (tid & 3) * 16;
        ushort4 o[4];
#pragma unroll
        for (int e = 0; e < 16; ++e)
            ((unsigned short*)o)[e] = tr[(r4 + e) * BN + c];
        unsigned short* dst = vTout + (size_t)(col0 - 1024 + c) * 1024 + row0 + r4;
        *(ushort4*)(dst + 0)  = o[0];
        *(ushort4*)(dst + 4)  = o[1];
        *(ushort4*)(dst + 8)  = o[2];
        *(ushort4*)(dst + 12) = o[3];
    } else {
        float* Cf = (float*)Cout + (OUTF32 ? bz * cBatch : 0);
        unsigned short* Cu = (unsigned short*)Cout + (OUTF32 ? 0 : bz * cBatch);
#pragma unroll
        for (int i = 0; i < MI; ++i) {
            const int rg = row0 + wm * (BM / 2) + i * 16 + (lane >> 4) * 4;
#pragma unroll
            for (int j = 0; j < NJ; ++j) {
                const int c = col0 + wn * (BN / 2) + j * 16 + (lane & 15);
                const float bi = BIAS ? bias[c] : 0.f;
                f32x4 v = acc[i][j];
#pragma unroll
                for (int r2 = 0; r2 < 4; ++r2) {
                    float val = v[r2] * alpha + bi;
                    if (RELU) val = fmaxf(val, 0.f);
                    if (RESID) val += resid[(size_t)(rg + r2) * ldr + c];
                    if (OUTF32) {
                        Cf[(size_t)(rg + r2) * ldc + c] = val;
                        if (BOTH) vTout[(size_t)(rg + r2) * ldc + c] = f2bf(val);
                    } else {
                        Cu[(size_t)(rg + r2) * ldc + c] = f2bf(val);
                    }
                }
            }
        }
    }
}

// ---------------------------------------------------------------------------
// Flash attention, round-14 KV-split: grid (16, NH, 2); block z handles K/V
// tiles [z*8, z*8+8) and writes RAW partial O (f32, un-normalized) plus
// per-row (m, l). flash_merge combines. Double-buffered K/V (validated r13).
// ---------------------------------------------------------------------------
__global__ __launch_bounds__(256) void flash_attn(
    const unsigned short* __restrict__ qkv,   // [1024][1536] (q|k|v)
    const unsigned short* __restrict__ vT,    // [512][1024]
    float* __restrict__ Of,                   // [2][1024][512]
    float* __restrict__ mlb)                  // [2][1024][2]
{
    __shared__ unsigned short Qs[64 * 64];
    __shared__ unsigned short Ks[2][64 * 64];
    __shared__ unsigned short Vs[2][64 * 64];
    __shared__ unsigned short Ps[64 * 64];

    const int tid = threadIdx.x, wave = tid >> 6, lane = tid & 63;
    const int q0 = blockIdx.x * 64;
    const int h  = blockIdx.y;
    const int z  = blockIdx.z;
    const int kt0 = z * 8;

    stage_tile<2>(qkv + (size_t)q0 * 1536 + h * 64, 1536, Qs, wave, lane);
    stage_tile<2>(qkv + 512 + (size_t)(kt0 * 64) * 1536 + h * 64, 1536, Ks[0], wave, lane);
    stage_tile<2>(vT + (size_t)(h * 64) * 1024 + kt0 * 64, 1024, Vs[0], wave, lane);
    __syncthreads();

    f32x4 Oacc[4];
#pragma unroll
    for (int j = 0; j < 4; ++j) Oacc[j] = (f32x4){0.f, 0.f, 0.f, 0.f};
    float mrow[4] = {-1e30f, -1e30f, -1e30f, -1e30f};
    float lrow[4] = {0.f, 0.f, 0.f, 0.f};

    for (int kt = 0; kt < 8; ++kt) {
        if (kt < 7) {
            stage_tile<2>(qkv + 512 + (size_t)((kt0 + kt + 1) * 64) * 1536 + h * 64, 1536,
                          Ks[(kt + 1) & 1], wave, lane);
            stage_tile<2>(vT + (size_t)(h * 64) * 1024 + (kt0 + kt + 1) * 64, 1024,
                          Vs[(kt + 1) & 1], wave, lane);
        }
        const unsigned short* Kc = Ks[kt & 1];
        const unsigned short* Vc = Vs[kt & 1];

        f32x4 s[4];
#pragma unroll
        for (int j = 0; j < 4; ++j) s[j] = (f32x4){0.f, 0.f, 0.f, 0.f};
#pragma unroll
        for (int ks = 0; ks < 2; ++ks) {
            const int kbase = ks * 64 + (lane >> 4) * 16;
            const int ra = wave * 16 + (lane & 15);
            short8 aq = *(const short8*)((const char*)Qs + ra * 128 + (kbase ^ ((ra & 7) << 4)));
#pragma unroll
            for (int j = 0; j < 4; ++j) {
                const int rb = j * 16 + (lane & 15);
                short8 bk8 = *(const short8*)((const char*)Kc + rb * 128 + (kbase ^ ((rb & 7) << 4)));
                s[j] = __builtin_amdgcn_mfma_f32_16x16x32_bf16(aq, bk8, s[j], 0, 0, 0);
            }
        }

        float f[4];
#pragma unroll
        for (int r = 0; r < 4; ++r) {
            float mx = -1e30f;
#pragma unroll
            for (int j = 0; j < 4; ++j) { s[j][r] *= 0.125f; mx = fmaxf(mx, s[j][r]); }
#pragma unroll
            for (int o = 1; o < 16; o <<= 1) mx = fmaxf(mx, __shfl_xor(mx, o));
            const float mn = fmaxf(mrow[r], mx);
            f[r] = expf(mrow[r] - mn);
            mrow[r] = mn;
            float sm = 0.f;
#pragma unroll
            for (int j = 0; j < 4; ++j) { s[j][r] = expf(s[j][r] - mn); sm += s[j][r]; }
#pragma unroll
            for (int o = 1; o < 16; o <<= 1) sm += __shfl_xor(sm, o);
            lrow[r] = lrow[r] * f[r] + sm;
        }
#pragma unroll
        for (int j = 0; j < 4; ++j)
#pragma unroll
            for (int r = 0; r < 4; ++r) Oacc[j][r] *= f[r];

        // P (C-layout) -> LDS (swizzled); wave-local stripe, no barrier needed
#pragma unroll
        for (int j = 0; j < 4; ++j) {
            const int col = (lane & 15) + j * 16;
#pragma unroll
            for (int r = 0; r < 4; ++r) {
                const int row = wave * 16 + (lane >> 4) * 4 + r;
                *(unsigned short*)((char*)Ps + row * 128 + ((col * 2) ^ ((row & 7) << 4))) =
                    f2bf(s[j][r]);
            }
        }

#pragma unroll
        for (int ks = 0; ks < 2; ++ks) {
            const int kbase = ks * 64 + (lane >> 4) * 16;
            const int ra = wave * 16 + (lane & 15);
            short8 ap = *(const short8*)((const char*)Ps + ra * 128 + (kbase ^ ((ra & 7) << 4)));
#pragma unroll
            for (int j = 0; j < 4; ++j) {
                const int rb = j * 16 + (lane & 15);
                short8 bv8 = *(const short8*)((const char*)Vc + rb * 128 + (kbase ^ ((rb & 7) << 4)));
                Oacc[j] = __builtin_amdgcn_mfma_f32_16x16x32_bf16(ap, bv8, Oacc[j], 0, 0, 0);
            }
        }
        __syncthreads();
    }

    // Write raw partial O (f32) + per-row m,l
    float* Oz = Of + (size_t)z * 524288;
#pragma unroll
    for (int j = 0; j < 4; ++j) {
        const int c = h * 64 + j * 16 + (lane & 15);
#pragma unroll
        for (int r = 0; r < 4; ++r) {
            const int row = q0 + wave * 16 + (lane >> 4) * 4 + r;
            Oz[(size_t)row * D_ + c] = Oacc[j][r];
        }
    }
    if ((lane & 15) == 0 && h == 0) { /* avoid 8x dup: only h==0? NO — m,l are per (row,h)! */ }
    // m,l are PER HEAD-ROW: store per (z,h,row): mlb layout [2][NH][1024][2]
    if ((lane & 15) == 0) {
#pragma unroll
        for (int r = 0; r < 4; ++r) {
            const int row = q0 + wave * 16 + (lane >> 4) * 4 + r;
            float* dst = mlb + (((size_t)z * NH + h) * 1024 + row) * 2;
            dst[0] = mrow[r];
            dst[1] = lrow[r];
        }
    }
}

// ---------------------------------------------------------------------------
// Merge the two KV-split partials: O = (a0*O0 + a1*O1) / (a0*l0 + a1*l1),
// a_z = exp(m_z - max(m0,m1)). m,l are per (head,row); O cols of head h are
// [h*64, h*64+64). One block per 4 rows; lane handles 8 dims.
// ---------------------------------------------------------------------------
__global__ __launch_bounds__(256) void flash_merge(
    const float* __restrict__ Of, const float* __restrict__ mlb,
    unsigned short* __restrict__ O)
{
    const int tid = threadIdx.x;
    const int row = blockIdx.x * 4 + (tid >> 6);
    const int lane = tid & 63;
    const int d0 = lane * 8;
    const int h = d0 >> 6;                    // head owning these 8 dims
    const float* ml0 = mlb + (((size_t)0 * NH + h) * 1024 + row) * 2;
    const float* ml1 = mlb + (((size_t)1 * NH + h) * 1024 + row) * 2;
    const float m0 = ml0[0], l0 = ml0[1], m1 = ml1[0], l1 = ml1[1];
    const float m = fmaxf(m0, m1);
    const float a0 = expf(m0 - m), a1 = expf(m1 - m);
    const float inv = 1.0f / (a0 * l0 + a1 * l1);
    const float* p0 = Of + (size_t)row * D_ + d0;
    const float* p1 = Of + 524288 + (size_t)row * D_ + d0;
    float4 x0 = *(const float4*)p0, x1 = *(const float4*)(p0 + 4);
    float4 y0 = *(const float4*)p1, y1 = *(const float4*)(p1 + 4);
    ushort4 o0, o1;
    o0.x = f2bf((a0 * x0.x + a1 * y0.x) * inv);
    o0.y = f2bf((a0 * x0.y + a1 * y0.y) * inv);
    o0.z = f2bf((a0 * x0.z + a1 * y0.z) * inv);
    o0.w = f2bf((a0 * x0.w + a1 * y0.w) * inv);
    o1.x = f2bf((a0 * x1.x + a1 * y1.x) * inv);
    o1.y = f2bf((a0 * x1.y + a1 * y1.y) * inv);
    o1.z = f2bf((a0 * x1.z + a1 * y1.z) * inv);
    o1.w = f2bf((a0 * x1.w + a1 * y1.w) * inv);
    *(ushort4*)(O + (size_t)row * D_ + d0) = o0;
    *(ushort4*)(O + (size_t)row * D_ + d0 + 4) = o1;
}

// ---------------------------------------------------------------------------
// LN over y = x(resid) + bias + sum of NZ split-K partials. One wave per row.
// ---------------------------------------------------------------------------
template<int NZ>
__global__ __launch_bounds__(64) void ln_sum_kernel(
    const float* __restrict__ y4,     // [NZ][1024][512]
    const float* __restrict__ bias,   // [512]
    const float* __restrict__ w, const float* __restrict__ b,
    float* __restrict__ x, unsigned short* __restrict__ xb)
{
    const int row = blockIdx.x;
    const int lane = threadIdx.x;
    const size_t off = (size_t)row * 512 + lane * 8;
    float vals[8];
#pragma unroll
    for (int j = 0; j < 8; ++j) vals[j] = x[off + j] + bias[lane * 8 + j];
#pragma unroll
    for (int z = 0; z < NZ; ++z) {
        float4 p0 = *(const float4*)(y4 + (size_t)z * 524288 + off);
        float4 p1 = *(const float4*)(y4 + (size_t)z * 524288 + off + 4);
        vals[0] += p0.x; vals[1] += p0.y; vals[2] += p0.z; vals[3] += p0.w;
        vals[4] += p1.x; vals[5] += p1.y; vals[6] += p1.z; vals[7] += p1.w;
    }
    float s = 0.f;
#pragma unroll
    for (int j = 0; j < 8; ++j) s += vals[j];
#pragma unroll
    for (int o = 32; o >= 1; o >>= 1) s += __shfl_xor(s, o);
    const float mu = s * (1.f / 512.f);
    float q = 0.f;
#pragma unroll
    for (int j = 0; j < 8; ++j) { float d = vals[j] - mu; q += d * d; }
#pragma unroll
    for (int o = 32; o >= 1; o >>= 1) q += __shfl_xor(q, o);
    const float inv = 1.0f / sqrtf(q * (1.f / 512.f) + EPS_);
    float ov[8];
#pragma unroll
    for (int j = 0; j < 8; ++j)
        ov[j] = (vals[j] - mu) * inv * w[lane * 8 + j] + b[lane * 8 + j];
    float4 o0 = {ov[0], ov[1], ov[2], ov[3]};
    float4 o1 = {ov[4], ov[5], ov[6], ov[7]};
    *(float4*)(x + off) = o0;
    *(float4*)(x + off + 4) = o1;
    ushort4 u0, u1;
    u0.x = f2bf(ov[0]); u0.y = f2bf(ov[1]); u0.z = f2bf(ov[2]); u0.w = f2bf(ov[3]);
    u1.x = f2bf(ov[4]); u1.y = f2bf(ov[5]); u1.z = f2bf(ov[6]); u1.w = f2bf(ov[7]);
    *(ushort4*)(xb + off) = u0;
    *(ushort4*)(xb + off + 4) = u1;
}

// ---------------------------------------------------------------------------
// Fused values+scatter: compute only the 2048 selected (r,c) dot products.
// ---------------------------------------------------------------------------
__global__ __launch_bounds__(256) void scatter_dot(
    const int* __restrict__ rows, const int* __restrict__ cols,
    const unsigned short* __restrict__ xb, __hip_bfloat16* __restrict__ out)
{
    const int k = blockIdx.x * 4 + (threadIdx.x >> 6);
    const int lane = threadIdx.x & 63;
    const int r = rows[k], c = cols[k];
    const unsigned short* xr = xb + (size_t)r * 512 + lane * 8;
    const unsigned short* xc = xb + (size_t)c * 512 + lane * 8;
    ushort4 a0 = *(const ushort4*)xr, a1 = *(const ushort4*)(xr + 4);
    ushort4 b0 = *(const ushort4*)xc, b1 = *(const ushort4*)(xc + 4);
    float s = bf2f(a0.x) * bf2f(b0.x) + bf2f(a0.y) * bf2f(b0.y) +
              bf2f(a0.z) * bf2f(b0.z) + bf2f(a0.w) * bf2f(b0.w) +
              bf2f(a1.x) * bf2f(b1.x) + bf2f(a1.y) * bf2f(b1.y) +
              bf2f(a1.z) * bf2f(b1.z) + bf2f(a1.w) * bf2f(b1.w);
#pragma unroll
    for (int o = 32; o >= 1; o >>= 1) s += __shfl_xor(s, o);
    if (lane == 0) {
        if (!(fabsf(s) < 1e30f)) s = 0.f;
        out[(size_t)r * 1024 + c] = __float2bfloat16(s);
    }
}

// ---------------------------------------------------------------------------
extern "C" void kernel_launch(void* const* d_in, const int* in_sizes, int n_in,
                              void* d_out, int out_size, void* d_ws, size_t ws_size,
                              hipStream_t stream)
{
    const float* ideal  = (const float*)d_in[0];
    const int*   rows   = (const int*)d_in[1];
    const int*   cols   = (const int*)d_in[2];
    const float* Wm     = (const float*)d_in[3];
    const float* bm     = (const float*)d_in[4];
    const float* Wphi1  = (const float*)d_in[5];
    const float* bphi1  = (const float*)d_in[6];
    const float* Wphi2  = (const float*)d_in[7];
    const float* bphi2  = (const float*)d_in[8];
    const float* Wrho1  = (const float*)d_in[9];
    const float* brho1  = (const float*)d_in[10];
    const float* Wrho2  = (const float*)d_in[11];
    const float* brho2  = (const float*)d_in[12];
    const float* Wq     = (const float*)d_in[13];
    const float* bq     = (const float*)d_in[14];
    const float* Wk     = (const float*)d_in[15];
    const float* bk     = (const float*)d_in[16];
    const float* Wv     = (const float*)d_in[17];
    const float* bv     = (const float*)d_in[18];
    const float* Wo     = (const float*)d_in[19];
    const float* bo     = (const float*)d_in[20];
    const float* ln1w   = (const float*)d_in[21];
    const float* ln1b   = (const float*)d_in[22];
    const float* W1     = (const float*)d_in[23];
    const float* b1     = (const float*)d_in[24];
    const float* W2     = (const float*)d_in[25];
    const float* b2     = (const float*)d_in[26];
    const float* ln2w   = (const float*)d_in[27];
    const float* ln2b   = (const float*)d_in[28];
    __hip_bfloat16* out = (__hip_bfloat16*)d_out;

    // ---- Workspace (MB offsets; ws_size = 256 MiB, round-6 evidence) ----
    char* base = (char*)d_ws;
    unsigned short* w_phi1 = (unsigned short*)(base + (0ll  << 20));
    unsigned short* w_phi2 = (unsigned short*)(base + (1ll  << 20));
    unsigned short* w_rho1 = (unsigned short*)(base + (3ll  << 20));
    unsigned short* w_rho2 = (unsigned short*)(base + (5ll  << 20));
    unsigned short* w_qkv  = (unsigned short*)(base + (6ll  << 20));
    unsigned short* w_o    = (unsigned short*)(base + (12ll << 20));
    unsigned short* w_1    = (unsigned short*)(base + (14ll << 20));
    unsigned short* w_2    = (unsigned short*)(base + (22ll << 20));
    float*          b_qkvc = (float*)         (base + (30ll << 20));
    unsigned short* h0b    = (unsigned short*)(base + (31ll << 20));  // 64MB
    unsigned short* h1b    = (unsigned short*)(base + (95ll << 20));  // 128MB
    float*          sbuf   = (float*)         (base + (223ll << 20)); // 4MB
    unsigned short* id_pad = (unsigned short*)(base + (227ll << 20)); // 8MB
    unsigned short* wm_pad = (unsigned short*)(base + (236ll << 20)); // 64KB
    unsigned short* sb_b   = (unsigned short*)(base + (31ll << 20));
    unsigned short* tb_b   = (unsigned short*)(base + (33ll << 20));
    float*          xbuf   = (float*)         (base + (35ll << 20));
    unsigned short* xb     = (unsigned short*)(base + (37ll << 20));
    unsigned short* qkvb   = (unsigned short*)(base + (40ll << 20));
    unsigned short* vT     = (unsigned short*)(base + (43ll << 20));
    unsigned short* ob     = (unsigned short*)(base + (44ll << 20));
    unsigned short* ffnt   = (unsigned short*)(base + (45ll << 20));  // 4MB
    float*          ysplit = (float*)         (base + (49ll << 20));  // 8MB (K-split partials)
    float*          Of     = (float*)         (base + (57ll << 20));  // 4MB (flash partials)
    float*          mlb    = (float*)         (base + (61ll << 20));  // 128KB

    // ---------------- One mega conversion launch (fill + all cvt + pads) ---
    mega_cvt<<<17936, 256, 0, stream>>>(
        Wphi1, Wphi2, Wrho1, Wrho2, Wo, W1, W2,
        w_phi1, w_phi2, w_rho1, w_rho2, w_o, w_1, w_2,
        Wq, Wk, Wv, bq, bk, bv, w_qkv, b_qkvc,
        ideal, id_pad, Wm, wm_pad, (unsigned short*)out);

    // ---------------- DeepSets ----------------
    // embed as K=64 MFMA GEMM
    mfma_nt<128, 128, 0, false, true, true, false, false, false, false, false>
        <<<dim3(4, 512), 256, 0, stream>>>(
        id_pad, 0, 64, wm_pad, 0, 64, bm, nullptr, 0, h0b, 0, D_, 64, 1.0f, nullptr);
    // phi1 (MODE 2, validated single-buffer path)
    mfma_nt<128, 128, 2, false, true, true, false, false, false, false, false>
        <<<4096, 256, 0, stream>>>(
        h0b, 0, D_, w_phi1, 0, D_, bphi1, nullptr, 0, h1b, 0, HID_, D_, 1.0f, nullptr);
    // phi2+pool (MODE 2)
    mfma_nt<128, 128, 2, true, true, true, true, false, false, false, false>
        <<<4096, 256, 0, stream>>>(
        h1b, 0, HID_, w_phi2, 0, HID_, bphi2, nullptr, 0, sbuf, 0, HID_, HID_, 1.0f, nullptr);

    // rho (64^2 tiles, DBUF); rho2 writes BOTH xbuf f32 + xb bf16
    cvt_bf16_kernel<<<1024, 256, 0, stream>>>(sbuf, sb_b, 262144);
    mfma_nt<64, 64, 0, false, true, true, false, false, false, true, false>
        <<<dim3(16, 16), 256, 0, stream>>>(
        sb_b, 0, HID_, w_rho1, 0, HID_, brho1, nullptr, 0, tb_b, 0, HID_, HID_, 1.0f, nullptr);
    mfma_nt<64, 64, 0, true, true, true, false, false, false, true, true>
        <<<dim3(8, 16), 256, 0, stream>>>(
        tb_b, 0, HID_, w_rho2, 0, HID_, brho2, nullptr, 0, xbuf, 0, D_, HID_, 1.0f, xb);

    // ---------------- Transformer ----------------
    for (int l = 0; l < NL; ++l) {
        // QKV fused (TRANSV writes vT for V-region blocks)
        mfma_nt<64, 64, 0, false, true, false, false, false, true, true, false>
            <<<dim3(24, 16), 256, 0, stream>>>(
            xb, 0, D_, w_qkv + (long long)l * 1536 * D_, 0, D_, b_qkvc + l * 1536,
            nullptr, 0, qkvb, 0, 1536, D_, 1.0f, vT);
        // flash attention KV-split-2 (raw partials) + merge
        flash_attn<<<dim3(16, NH, 2), 256, 0, stream>>>(qkvb, vT, Of, mlb);
        flash_merge<<<256, 256, 0, stream>>>(Of, mlb, ob);
        // Wo split-K=2 -> ysplit partials; ln_sum<2> folds bias+resid+LN1
        mfma_nt<64, 64, 0, true, false, false, false, false, false, true, false>
            <<<dim3(8, 16, 2), 256, 0, stream>>>(
            ob, 256, D_, w_o + (long long)l * D_ * D_, 256, D_, nullptr,
            nullptr, 0, ysplit, 524288, D_, 256, 1.0f, nullptr);
        ln_sum_kernel<2><<<NP, 64, 0, stream>>>(ysplit, bo + l * D_,
                                                ln1w + l * D_, ln1b + l * D_, xbuf, xb);
        // ffn1: xb @ W1^T + b1, relu -> bf16
        mfma_nt<64, 64, 0, false, true, true, false, false, false, true, false>
            <<<dim3(32, 16), 256, 0, stream>>>(
            xb, 0, D_, w_1 + (long long)l * FF_ * D_, 0, D_, b1 + l * FF_,
            nullptr, 0, ffnt, 0, FF_, D_, 1.0f, nullptr);
        // ffn2 split-K=4 -> ysplit partials; ln_sum<4> folds bias+resid+LN2
        mfma_nt<64, 64, 0, true, false, false, false, false, false, true, false>
            <<<dim3(8, 16, 4), 256, 0, stream>>>(
            ffnt, 512, FF_, w_2 + (long long)l * D_ * FF_, 512, FF_, nullptr,
            nullptr, 0, ysplit, 524288, D_, 512, 1.0f, nullptr);
        ln_sum_kernel<4><<<NP, 64, 0, stream>>>(ysplit, b2 + l * D_,
                                                ln2w + l * D_, ln2b + l * D_, xbuf, xb);
    }

    // scatter: out[r,c] = dot(x[r], x[c]) for the 2048 selected pairs only
    scatter_dot<<<NK / 4, 256, 0, stream>>>(rows, cols, xb, out);
}